// Round 2
// baseline (161.096 us; speedup 1.0000x reference)
//
#include <hip/hip_runtime.h>
#include <hip/hip_bf16.h>

// SAGAN self-attention v6. B=8, C=64, N=4096, CQ=8.
// Algebraic refactor: out = Wv.(X.P^T)/d + bv  -- V never materialized.
// prep: bf16 cast of x (Xb) + Q/K projection (Q pre-scaled by log2(e)).
// attn v6 (vs v4 63us / v5 82us):
//   - v5 post-mortem: __launch_bounds__(256,4) forced arch-VGPR to 64 ->
//     spills (+2MB scratch writes, VALUBusy 45->26). REMOVED. v4's P
//     layout (stride 16 dwords + XOR swz) re-derived as conflict-OPTIMAL
//     (b64 writes 4-deep, b128 reads 8-deep = HW minimum). RESTORED.
//   - v4 was grid-capped at 2 blocks/CU (512 blocks). v6 splits j into
//     2 halves AND keeps i-tile 32: grid 2048 = 8 blocks/CU of work,
//     ~88-reg working set fits <=128 naturally -> 3-4 waves/SIMD.
//   - Each block: 16 steps x 32 j per wave; O' [64c][32q] partial + 32
//     denom partials -> workspace; combine kernel sums 2 j-halves and
//     runs the Wv epilogue GEMM.

#define B_   8
#define C_   64
#define N_   4096
#define LOG2E 1.44269504088896340736f

typedef short bf16x8 __attribute__((ext_vector_type(8)));
typedef float f32x4  __attribute__((ext_vector_type(4)));
typedef unsigned int uint32;

#if __has_builtin(__builtin_amdgcn_exp2f)
#define EXP2(x) __builtin_amdgcn_exp2f(x)
#else
#define EXP2(x) __expf((x) * 0.69314718055994530942f)
#endif

__device__ __forceinline__ unsigned short f2bf_rn(float f) {
    union { __hip_bfloat16 h; unsigned short u; } cv;
    cv.h = __float2bfloat16(f);
    return cv.u;
}
__device__ __forceinline__ uint32 pk_rn(float lo, float hi) {
    return (uint32)f2bf_rn(lo) | ((uint32)f2bf_rn(hi) << 16);
}
// RTZ pack (1 v_perm): bias cancels in softmax ratio. Verified R2/R3.
__device__ __forceinline__ uint32 pack_rtz(float lo, float hi) {
    return __builtin_amdgcn_perm(__float_as_uint(hi), __float_as_uint(lo), 0x07060302);
}

// ---------------------------------------------------------------------------
// prep: UNCHANGED from v4/v5 (isolation: if prep is the hidden ~55us of
// dur_us, it will surface in the top-5 once attn drops below it).
// ---------------------------------------------------------------------------
__global__ __launch_bounds__(256) void prep_kernel(
    const float* __restrict__ x,
    const float* __restrict__ wq, const float* __restrict__ bq,
    const float* __restrict__ wk, const float* __restrict__ bk,
    unsigned short* __restrict__ Qh, unsigned short* __restrict__ Kh,
    unsigned short* __restrict__ Xb)
{
    __shared__ float Xs[C_][64];
    __shared__ float Wqk[16][C_];
    __shared__ float Bqk[16];

    const int t  = threadIdx.x;
    const int b  = blockIdx.x >> 6;
    const int p0 = (blockIdx.x & 63) << 6;

    for (int i = t; i < 1024; i += 256) {
        int o = i >> 6;
        Wqk[o][i & 63] = (o < 8) ? wq[i] * LOG2E : wk[i - 512];
    }
    if (t < 16) Bqk[t] = (t < 8) ? bq[t] * LOG2E : bk[t - 8];

    for (int i = t; i < 2048; i += 256) {
        int c = i >> 5, p2 = (i & 31) << 1;
        const float* xp = x + ((size_t)b * C_ + c) * N_ + p0 + p2;
        float2 v = *(const float2*)xp;
        Xs[c][p2] = v.x; Xs[c][p2 + 1] = v.y;
        *(uint32*)(Xb + ((size_t)b * C_ + c) * N_ + p0 + p2) = pk_rn(v.x, v.y);
    }
    __syncthreads();

    const int pix = t & 63, grp = t >> 6;
    float a[4];
    #pragma unroll
    for (int r = 0; r < 4; ++r) a[r] = Bqk[grp * 4 + r];
    for (int c = 0; c < C_; ++c) {
        float xv = Xs[c][pix];
        #pragma unroll
        for (int r = 0; r < 4; ++r) a[r] += Wqk[grp * 4 + r][c] * xv;
    }
    #pragma unroll
    for (int r = 0; r < 4; ++r) {
        int o = grp * 4 + r;
        unsigned short hv = f2bf_rn(a[r]);
        if (o < 8) Qh[((size_t)b * N_ + p0 + pix) * 8 + o] = hv;
        else       Kh[((size_t)b * N_ + p0 + pix) * 8 + (o - 8)] = hv;
    }
}

// ---------------------------------------------------------------------------
// attn v6: grid B*(N/32)*2 = 2048 blocks (b, 32-query tile, j-half),
// 256 threads (4 waves). Wave w: j in [jh*2048 + w*512, +512), both
// q-tiles, all 64 channels. 16 steps x 32 j. NO launch_bounds min-waves
// (v5 lesson: forcing waves/EU spills the unified VGPR/AGPR file).
// ---------------------------------------------------------------------------
__global__ __launch_bounds__(256) void attn_mfma5_kernel(
    const unsigned short* __restrict__ Qh,
    const unsigned short* __restrict__ Kh,
    const unsigned short* __restrict__ Xb,
    float* __restrict__ O_part, float* __restrict__ D_part)
{
    // LDS map (16896 B, LDS never the occupancy cap):
    //  loop:   [0,8K)      P: wave w at w*2048 + qt*1024 + l16*64 + swz
    //                      (v4 layout: b64 writes 4-deep, b128 reads
    //                       8-deep per bank = HW minimum, conflict-optimal)
    //          [8K,16K)    dump buffer (one wave's acc = 8KB)
    //          [16K,+512)  Dn [4][32] fp32
    __shared__ __align__(16) char smem[16896];

    const int t    = threadIdx.x;
    const int w    = t >> 6;
    const int lane = t & 63;
    const int l16  = lane & 15;
    const int qd   = lane >> 4;
    const int b    = blockIdx.x >> 8;
    const int rr_  = blockIdx.x & 255;
    const int i0   = (rr_ >> 1) << 5;
    const int jh   = rr_ & 1;
    const int j0   = jh * 2048 + w * 512;

    const bf16x8 z8 = {};
    const f32x4  zf = {};

    // Q frags (phase-1 B-operand, B[k=ch][n=q], quads 1-3 zero: K-pad)
    bf16x8 qf[2];
    #pragma unroll
    for (int qt = 0; qt < 2; ++qt) {
        qf[qt] = z8;
        if (qd == 0)
            qf[qt] = *(const bf16x8*)(Qh + ((size_t)b * N_ + i0 + qt * 16 + l16) * 8);
    }

    const unsigned short* Kp = Kh + ((size_t)b * N_ + j0) * 8;
    const unsigned short* Xp = Xb + (size_t)b * C_ * N_ + j0;

    f32x4 acc[4][2];   // [ct][qt]: O'(c=ct*16+qd*4+r, q=qt*16+l16)
    #pragma unroll
    for (int ct = 0; ct < 4; ++ct)
        #pragma unroll
        for (int qt = 0; qt < 2; ++qt) acc[ct][qt] = zf;
    float dsum[2] = {0.f, 0.f};

    // wave-private P addressing (v4-proven, conflict-optimal)
    const int swz   = (l16 & 3) << 2;
    const int wbase = w * 2048 + l16 * 64;
    int woff[2];
    #pragma unroll
    for (int jt = 0; jt < 2; ++jt) woff[jt] = ((jt * 8 + qd * 2) ^ swz) << 2;
    const int roff = ((qd * 4) ^ swz) << 2;

    // preload step 0
    bf16x8 kf[2][2], xf[2][4];
    #pragma unroll
    for (int jt = 0; jt < 2; ++jt) {
        kf[0][jt] = z8;
        if (qd == 0) kf[0][jt] = *(const bf16x8*)(Kp + (jt * 16 + l16) * 8);
    }
    #pragma unroll
    for (int ct = 0; ct < 4; ++ct)
        xf[0][ct] = *(const bf16x8*)(Xp + (size_t)(ct * 16 + l16) * N_ + qd * 8);

    #pragma unroll 2
    for (int s = 0; s < 16; ++s) {
        const int cur = s & 1, nxt = cur ^ 1;
        const int jb = s * 32;

        // phase 1: S^T[j][q] (rows j=jt*16+qd*4+r, col q=l16)
        f32x4 sf[2][2];
        #pragma unroll
        for (int jt = 0; jt < 2; ++jt)
            #pragma unroll
            for (int qt = 0; qt < 2; ++qt)
                sf[jt][qt] = __builtin_amdgcn_mfma_f32_16x16x32_bf16(kf[cur][jt], qf[qt], zf, 0, 0, 0);

        // prefetch next step's K and X frags (latency hidden behind exp/p2)
        if (s < 15) {
            #pragma unroll
            for (int jt = 0; jt < 2; ++jt) {
                bf16x8 nk = z8;
                if (qd == 0) nk = *(const bf16x8*)(Kp + (size_t)(jb + 32 + jt * 16 + l16) * 8);
                kf[nxt][jt] = nk;
            }
            #pragma unroll
            for (int ct = 0; ct < 4; ++ct)
                xf[nxt][ct] = *(const bf16x8*)(Xp + (size_t)(ct * 16 + l16) * N_ + jb + 32 + qd * 8);
        }

        // exp2 -> denom + pack to wave-private LDS
        #pragma unroll
        for (int jt = 0; jt < 2; ++jt)
            #pragma unroll
            for (int qt = 0; qt < 2; ++qt) {
                float e0 = EXP2(sf[jt][qt][0]);
                float e1 = EXP2(sf[jt][qt][1]);
                float e2 = EXP2(sf[jt][qt][2]);
                float e3 = EXP2(sf[jt][qt][3]);
                dsum[qt] += (e0 + e1) + (e2 + e3);
                uint2 u;
                u.x = pack_rtz(e0, e1);
                u.y = pack_rtz(e2, e3);
                *(uint2*)(smem + wbase + qt * 1024 + woff[jt]) = u;
            }

        // phase 2: O' += X . P^T  (A=X[m=c][k=j], B=P^T[k=j][n=q])
        #pragma unroll
        for (int qt = 0; qt < 2; ++qt) {
            bf16x8 pb = *(const bf16x8*)(smem + wbase + qt * 1024 + roff);
            #pragma unroll
            for (int ct = 0; ct < 4; ++ct)
                acc[ct][qt] = __builtin_amdgcn_mfma_f32_16x16x32_bf16(xf[cur][ct], pb, acc[ct][qt], 0, 0, 0);
        }
    }

    // ---- denominator partials -> Dn[w][32] ----
    #pragma unroll
    for (int qt = 0; qt < 2; ++qt) {
        float v = dsum[qt];
        v += __shfl_xor(v, 16, 64);
        v += __shfl_xor(v, 32, 64);
        if (qd == 0) *(float*)(smem + 16384 + (w * 32 + qt * 16 + l16) * 4) = v;
    }

    // ---- cross-wave O' reduce: w1 pre-dumps to [8K,16K) (untouched in
    //      loop); P region [0,8K) reused after S1. 3 barriers total. ----
    if (w == 1) {
        #pragma unroll
        for (int ct = 0; ct < 4; ++ct)
            #pragma unroll
            for (int qt = 0; qt < 2; ++qt)
                *(f32x4*)(smem + 8192 + (ct * 2 + qt) * 1024 + lane * 16) = acc[ct][qt];
    }
    __syncthreads();                                   // S1
    if (w == 0) {
        #pragma unroll
        for (int ct = 0; ct < 4; ++ct)
            #pragma unroll
            for (int qt = 0; qt < 2; ++qt)
                acc[ct][qt] += *(const f32x4*)(smem + 8192 + (ct * 2 + qt) * 1024 + lane * 16);
    }
    if (w == 2) {
        #pragma unroll
        for (int ct = 0; ct < 4; ++ct)
            #pragma unroll
            for (int qt = 0; qt < 2; ++qt)
                *(f32x4*)(smem + (ct * 2 + qt) * 1024 + lane * 16) = acc[ct][qt];
    }
    __syncthreads();                                   // S2
    if (w == 0) {
        #pragma unroll
        for (int ct = 0; ct < 4; ++ct)
            #pragma unroll
            for (int qt = 0; qt < 2; ++qt)
                acc[ct][qt] += *(const f32x4*)(smem + (ct * 2 + qt) * 1024 + lane * 16);
    }
    if (w == 3) {
        #pragma unroll
        for (int ct = 0; ct < 4; ++ct)
            #pragma unroll
            for (int qt = 0; qt < 2; ++qt)
                *(f32x4*)(smem + 8192 + (ct * 2 + qt) * 1024 + lane * 16) = acc[ct][qt];
    }
    __syncthreads();                                   // S3
    if (w == 0) {
        #pragma unroll
        for (int ct = 0; ct < 4; ++ct)
            #pragma unroll
            for (int qt = 0; qt < 2; ++qt)
                acc[ct][qt] += *(const f32x4*)(smem + 8192 + (ct * 2 + qt) * 1024 + lane * 16);

        // write O' partial [64c][32q] fp32 (8 KB) to workspace
        float* Op = O_part + (size_t)blockIdx.x * 2048;
        #pragma unroll
        for (int ct = 0; ct < 4; ++ct)
            #pragma unroll
            for (int qt = 0; qt < 2; ++qt)
                #pragma unroll
                for (int r = 0; r < 4; ++r)
                    Op[(ct * 16 + qd * 4 + r) * 32 + qt * 16 + l16] = acc[ct][qt][r];

        // denom partial (summed over 4 waves)
        if (lane < 32) {
            const float* Dn = (const float*)(smem + 16384);
            D_part[(size_t)blockIdx.x * 32 + lane] =
                Dn[lane] + Dn[32 + lane] + Dn[64 + lane] + Dn[96 + lane];
        }
    }
}

// ---------------------------------------------------------------------------
// combine: grid B*(N/32) = 1024 blocks, 256 threads. Sums the 2 j-half
// partials, then out = Wv.O'/d + bv (fp32 GEMM from LDS, v4 epilogue).
// ---------------------------------------------------------------------------
__global__ __launch_bounds__(256) void combine_kernel(
    const float* __restrict__ O_part, const float* __restrict__ D_part,
    const float* __restrict__ wv, const float* __restrict__ bv,
    float* __restrict__ out)
{
    __shared__ __align__(16) char smem[24704];
    float* Wvs = (float*)smem;              // [64][64]
    float* Or  = (float*)(smem + 16384);    // [64][32]
    float* inv = (float*)(smem + 24576);    // [32]

    const int t  = threadIdx.x;
    const int c  = blockIdx.x;
    const int b  = c >> 7;
    const int i0 = (c & 127) << 5;

    const f32x4* PA = (const f32x4*)(O_part + (size_t)c * 4096);
    const f32x4* PB = PA + 512;
    f32x4* Or4 = (f32x4*)Or;
    #pragma unroll
    for (int k = 0; k < 2; ++k) {
        int i = t + k * 256;
        Or4[i] = PA[i] + PB[i];
    }
    #pragma unroll
    for (int k = 0; k < 4; ++k) {
        int i = t + k * 256;
        ((f32x4*)Wvs)[i] = ((const f32x4*)wv)[i];
    }
    if (t < 32) inv[t] = 1.0f / (D_part[c * 64 + t] + D_part[c * 64 + 32 + t]);
    __syncthreads();

    const int q = t & 31, grp = t >> 5;
    float o[8];
    #pragma unroll
    for (int r = 0; r < 8; ++r) o[r] = 0.f;
    for (int k = 0; k < 64; ++k) {
        float ov = Or[k * 32 + q];                      // 2-way broadcast: free
        #pragma unroll
        for (int r = 0; r < 8; ++r)
            o[r] += Wvs[(grp * 8 + r) * 64 + k] * ov;   // broadcast
    }
    const float iv = inv[q];
    #pragma unroll
    for (int r = 0; r < 8; ++r)
        out[((size_t)b * C_ + grp * 8 + r) * N_ + i0 + q] = o[r] * iv + bv[grp * 8 + r];
}

// ---------------------------------------------------------------------------
// Fallback (workspace too small): round-1 fused fp32 flash kernel (verified).
// ---------------------------------------------------------------------------
__global__ __launch_bounds__(256) void attn_fused_fallback(
    const float* __restrict__ x,
    const float* __restrict__ wq, const float* __restrict__ bq,
    const float* __restrict__ wk, const float* __restrict__ bk,
    const float* __restrict__ wv, const float* __restrict__ bv,
    float* __restrict__ out)
{
    __shared__ float Qs[64][8];
    __shared__ float Ks[8][64];
    __shared__ float Vs[64][C_];
    __shared__ float Ws[64][64 + 1];
    __shared__ float Xs[C_ * 64];
    __shared__ float Wks[8][C_];
    __shared__ float Wvs[C_][C_ + 1];

    const int t     = threadIdx.x;
    const int b     = blockIdx.x / (N_ / 64);
    const int i0    = (blockIdx.x % (N_ / 64)) * 64;
    const int jlane = t & 63;
    const int wgrp  = t >> 6;

    for (int l = t; l < 8 * C_;  l += 256) Wks[l >> 6][l & 63] = wk[l];
    for (int l = t; l < C_ * C_; l += 256) Wvs[l >> 6][l & 63] = wv[l];
    for (int l = t; l < C_ * 64; l += 256)
        Xs[(l >> 6) * 64 + (l & 63)] = x[((size_t)b * C_ + (l >> 6)) * N_ + i0 + (l & 63)];
    __syncthreads();
    {
        int qi = jlane;
        #pragma unroll
        for (int r = 0; r < 2; ++r) {
            int cc = wgrp * 2 + r;
            float a = bq[cc];
            for (int c = 0; c < C_; ++c) a += wq[cc * C_ + c] * Xs[c * 64 + qi];
            Qs[qi][cc] = a;
        }
    }
    __syncthreads();

    const int qi2 = t >> 2;
    const int cb  = (t & 3) << 4;
    float accv[16];
    #pragma unroll
    for (int r = 0; r < 16; ++r) accv[r] = 0.f;
    float denom = 0.f;

    for (int j0 = 0; j0 < N_; j0 += 64) {
        for (int l = t; l < C_ * 64; l += 256)
            Xs[(l >> 6) * 64 + (l & 63)] = x[((size_t)b * C_ + (l >> 6)) * N_ + j0 + (l & 63)];
        __syncthreads();
        {
            int j = jlane;
            #pragma unroll
            for (int r = 0; r < 2; ++r) {
                int cc = wgrp * 2 + r;
                float a = bk[cc];
                for (int c = 0; c < C_; ++c) a += Wks[cc][c] * Xs[c * 64 + j];
                Ks[cc][j] = a;
            }
        }
        {
            int vc = jlane;
            #pragma unroll 2
            for (int r = 0; r < 16; ++r) {
                int j = wgrp * 16 + r;
                float a = bv[vc];
                for (int c = 0; c < C_; ++c) a += Wvs[vc][c] * Xs[c * 64 + j];
                Vs[j][vc] = a;
            }
        }
        __syncthreads();
        {
            float kreg[8];
            #pragma unroll
            for (int cc = 0; cc < 8; ++cc) kreg[cc] = Ks[cc][jlane];
            #pragma unroll 4
            for (int r = 0; r < 16; ++r) {
                int qi = wgrp * 16 + r;
                float e = 0.f;
                #pragma unroll
                for (int cc = 0; cc < 8; ++cc) e += Qs[qi][cc] * kreg[cc];
                Ws[qi][jlane] = __expf(e);
            }
        }
        __syncthreads();
        #pragma unroll 4
        for (int j = 0; j < 64; ++j) {
            float wv2 = Ws[qi2][j];
            denom += wv2;
            const float4* vrow = (const float4*)(&Vs[j][cb]);
            float4 v0 = vrow[0], v1 = vrow[1], v2 = vrow[2], v3 = vrow[3];
            accv[0]  += wv2 * v0.x; accv[1]  += wv2 * v0.y; accv[2]  += wv2 * v0.z; accv[3]  += wv2 * v0.w;
            accv[4]  += wv2 * v1.x; accv[5]  += wv2 * v1.y; accv[6]  += wv2 * v1.z; accv[7]  += wv2 * v1.w;
            accv[8]  += wv2 * v2.x; accv[9]  += wv2 * v2.y; accv[10] += wv2 * v2.z; accv[11] += wv2 * v2.w;
            accv[12] += wv2 * v3.x; accv[13] += wv2 * v3.y; accv[14] += wv2 * v3.z; accv[15] += wv2 * v3.w;
        }
        __syncthreads();
    }

    const float inv = 1.0f / denom;
    #pragma unroll
    for (int r = 0; r < 16; ++r)
        out[((size_t)b * C_ + cb + r) * N_ + i0 + qi2] = accv[r] * inv;
}

// ---------------------------------------------------------------------------
extern "C" void kernel_launch(void* const* d_in, const int* in_sizes, int n_in,
                              void* d_out, int out_size, void* d_ws, size_t ws_size,
                              hipStream_t stream)
{
    const float* x  = (const float*)d_in[0];
    const float* wq = (const float*)d_in[1];
    const float* bq = (const float*)d_in[2];
    const float* wk = (const float*)d_in[3];
    const float* bk = (const float*)d_in[4];
    const float* wv = (const float*)d_in[5];
    const float* bv = (const float*)d_in[6];
    float* out = (float*)d_out;

    const size_t nQ = (size_t)B_ * N_ * 8;        // 256K elems
    const size_t nX = (size_t)B_ * C_ * N_;       // 2M elems
    const size_t baseB = (2 * nQ + nX) * sizeof(unsigned short);  // 5 MB
    const size_t nPartBlk = (size_t)B_ * (N_ / 32) * 2;           // 2048
    const size_t oBytes = nPartBlk * 2048 * sizeof(float);        // 16 MB
    const size_t dBytes = nPartBlk * 32 * sizeof(float);          // 256 KB
    const size_t needed = baseB + oBytes + dBytes;

    if (ws_size >= needed) {
        unsigned short* Qh = (unsigned short*)d_ws;
        unsigned short* Kh = Qh + nQ;
        unsigned short* Xb = Kh + nQ;
        float* O_part = (float*)((char*)d_ws + baseB);
        float* D_part = O_part + nPartBlk * 2048;
        prep_kernel<<<B_ * (N_ / 64), 256, 0, stream>>>(x, wq, bq, wk, bk, Qh, Kh, Xb);
        attn_mfma5_kernel<<<(int)nPartBlk, 256, 0, stream>>>(Qh, Kh, Xb, O_part, D_part);
        combine_kernel<<<B_ * (N_ / 32), 256, 0, stream>>>(O_part, D_part, wv, bv, out);
    } else {
        attn_fused_fallback<<<B_ * (N_ / 64), 256, 0, stream>>>(x, wq, bq, wk, bk, wv, bv, out);
    }
}

// Round 3
// 141.746 us; speedup vs baseline: 1.1365x; 1.1365x over previous
//
#include <hip/hip_runtime.h>
#include <hip/hip_bf16.h>

// SAGAN self-attention v7. B=8, C=64, N=4096, CQ=8.
// Algebraic refactor: out = Wv.(X.P^T)/d + bv  -- V never materialized.
// v7 = v4 structure EXACT (63.2us attn; v5/v6 restructures both regressed)
// + three safe levers:
//   (1) denominator via ones-row MFMA (d[q] = sum_j P[j][q]): +4 MFMA/step
//       on the 16%-busy matrix pipe, deletes 24 dependent VALU adds/step
//       and the epilogue shfl tree. Num & denom now both use RTZ bf16 P.
//   (2) unmasked kf loads: qf is exactly zero for k>=8 lanes, so K-pad
//       lanes may hold finite garbage (0 x garbage = 0). Deletes per-step
//       exec-mask + zero-movs.
//   (3) XCD-aware block swizzle (512%8==0, bijective): one batch per XCD
//       L2 (~650KB panel) instead of all 8. + s_setprio around MFMA
//       clusters (waves desynced in loop -> T5-favorable).

#define B_   8
#define C_   64
#define N_   4096
#define LOG2E 1.44269504088896340736f

typedef short bf16x8 __attribute__((ext_vector_type(8)));
typedef float f32x4  __attribute__((ext_vector_type(4)));
typedef unsigned int uint32;

#if __has_builtin(__builtin_amdgcn_exp2f)
#define EXP2(x) __builtin_amdgcn_exp2f(x)
#else
#define EXP2(x) __expf((x) * 0.69314718055994530942f)
#endif

__device__ __forceinline__ unsigned short f2bf_rn(float f) {
    union { __hip_bfloat16 h; unsigned short u; } cv;
    cv.h = __float2bfloat16(f);
    return cv.u;
}
__device__ __forceinline__ uint32 pk_rn(float lo, float hi) {
    return (uint32)f2bf_rn(lo) | ((uint32)f2bf_rn(hi) << 16);
}
// RTZ pack (1 v_perm): bias cancels in softmax ratio. Verified R2/R3.
__device__ __forceinline__ uint32 pack_rtz(float lo, float hi) {
    return __builtin_amdgcn_perm(__float_as_uint(hi), __float_as_uint(lo), 0x07060302);
}

// ---------------------------------------------------------------------------
// prep: UNCHANGED from v4 (byte-identical; isolation of the non-attn gap).
// ---------------------------------------------------------------------------
__global__ __launch_bounds__(256) void prep_kernel(
    const float* __restrict__ x,
    const float* __restrict__ wq, const float* __restrict__ bq,
    const float* __restrict__ wk, const float* __restrict__ bk,
    unsigned short* __restrict__ Qh, unsigned short* __restrict__ Kh,
    unsigned short* __restrict__ Xb)
{
    __shared__ float Xs[C_][64];
    __shared__ float Wqk[16][C_];
    __shared__ float Bqk[16];

    const int t  = threadIdx.x;
    const int b  = blockIdx.x >> 6;
    const int p0 = (blockIdx.x & 63) << 6;

    for (int i = t; i < 1024; i += 256) {
        int o = i >> 6;
        Wqk[o][i & 63] = (o < 8) ? wq[i] * LOG2E : wk[i - 512];
    }
    if (t < 16) Bqk[t] = (t < 8) ? bq[t] * LOG2E : bk[t - 8];

    for (int i = t; i < 2048; i += 256) {
        int c = i >> 5, p2 = (i & 31) << 1;
        const float* xp = x + ((size_t)b * C_ + c) * N_ + p0 + p2;
        float2 v = *(const float2*)xp;
        Xs[c][p2] = v.x; Xs[c][p2 + 1] = v.y;
        *(uint32*)(Xb + ((size_t)b * C_ + c) * N_ + p0 + p2) = pk_rn(v.x, v.y);
    }
    __syncthreads();

    const int pix = t & 63, grp = t >> 6;
    float a[4];
    #pragma unroll
    for (int r = 0; r < 4; ++r) a[r] = Bqk[grp * 4 + r];
    for (int c = 0; c < C_; ++c) {
        float xv = Xs[c][pix];
        #pragma unroll
        for (int r = 0; r < 4; ++r) a[r] += Wqk[grp * 4 + r][c] * xv;
    }
    #pragma unroll
    for (int r = 0; r < 4; ++r) {
        int o = grp * 4 + r;
        unsigned short hv = f2bf_rn(a[r]);
        if (o < 8) Qh[((size_t)b * N_ + p0 + pix) * 8 + o] = hv;
        else       Kh[((size_t)b * N_ + p0 + pix) * 8 + (o - 8)] = hv;
    }
}

// ---------------------------------------------------------------------------
// attn v7: grid B * N/64 = 512 blocks (XCD-swizzled), 256 threads (4 waves).
// Wave w: j in [w*1024, w*1024+1024), all 4 q-tiles, all 64 channels.
// ---------------------------------------------------------------------------
__global__ __launch_bounds__(256) void attn_mfma6_kernel(
    const unsigned short* __restrict__ Qh,
    const unsigned short* __restrict__ Kh,
    const unsigned short* __restrict__ Xb,
    const float* __restrict__ wv, const float* __restrict__ bv,
    float* __restrict__ out)
{
    // [0,16K): per-wave Ps (4KB each); epilogue: Wvs fp32 [64][64]
    // [16K,32K): RED r=0, then Or fp32 [64][64]
    // [32K,48K): RED r=1 ; [48K,64K): RED r=2 ; [64K,+1K): Dn [4][64]
    __shared__ __align__(16) char smem[66560];

    const int t    = threadIdx.x;
    const int w    = t >> 6;
    const int lane = t & 63;
    const int l16  = lane & 15;
    const int qd   = lane >> 4;
    // XCD swizzle: dispatch slot s -> XCD s%8; give XCD k the 64 blocks of
    // batch k so its 4MB L2 holds exactly one batch's Xb/Qh/Kh panel.
    const int nb   = ((blockIdx.x & 7) << 6) | (blockIdx.x >> 3);
    const int b    = nb >> 6;
    const int i0   = (nb & 63) << 6;

    const bf16x8 z8 = {};
    const f32x4  zf = {};
    const short ONE_BF = (short)0x3F80;              // bf16 1.0
    const bf16x8 ones = {ONE_BF, ONE_BF, ONE_BF, ONE_BF,
                         ONE_BF, ONE_BF, ONE_BF, ONE_BF};

    // Q frags (phase-1 B-operand, B[k=ch][n=q], quads 1-3 ZERO: this is
    // what makes unmasked kf garbage safe -- 0 * finite = 0).
    bf16x8 qf[4];
    #pragma unroll
    for (int qt = 0; qt < 4; ++qt) {
        qf[qt] = z8;
        if (qd == 0)
            qf[qt] = *(const bf16x8*)(Qh + ((size_t)b * N_ + i0 + qt * 16 + l16) * 8);
    }

    const unsigned short* Kp = Kh + ((size_t)b * N_ + w * 1024) * 8;
    const unsigned short* Xp = Xb + (size_t)b * C_ * N_ + w * 1024;

    f32x4 acc[4][4];   // [ct][qt]: O'(c=ct*16+qd*4+r, q=qt*16+l16)
    #pragma unroll
    for (int ct = 0; ct < 4; ++ct)
        #pragma unroll
        for (int qt = 0; qt < 4; ++qt) acc[ct][qt] = zf;
    f32x4 acc_d[4];    // ones-row GEMM: every row = d_partial[q=qt*16+l16]
    #pragma unroll
    for (int qt = 0; qt < 4; ++qt) acc_d[qt] = zf;

    // wave-private P addressing, XOR-swizzled (b64 writes & b128 reads at
    // the HW-minimum 4-deep/8-deep bank cascade -- conflict-optimal)
    const int swz   = (l16 & 3) << 2;
    const int wbase = w * 4096 + l16 * 64;
    int woff[2];
    #pragma unroll
    for (int jt = 0; jt < 2; ++jt) woff[jt] = ((jt * 8 + qd * 2) ^ swz) << 2;
    const int roff = ((qd * 4) ^ swz) << 2;

    // preload step 0 (kf UNMASKED: all lanes load row l16's 16B; qd>=1
    // lanes hold ch0-7 copies feeding k=8..31 against qf zeros -> 0)
    bf16x8 kf[2][2], xf[2][4];
    #pragma unroll
    for (int jt = 0; jt < 2; ++jt)
        kf[0][jt] = *(const bf16x8*)(Kp + (jt * 16 + l16) * 8);
    #pragma unroll
    for (int ct = 0; ct < 4; ++ct)
        xf[0][ct] = *(const bf16x8*)(Xp + (size_t)(ct * 16 + l16) * N_ + qd * 8);

    #pragma unroll 2
    for (int s = 0; s < 32; ++s) {
        const int cur = s & 1, nxt = cur ^ 1;
        const int jb = s * 32;

        // phase 1: S^T[j][q] (rows j=jt*16+qd*4+r, col q=l16)
        f32x4 sf[2][4];
        __builtin_amdgcn_s_setprio(1);
        #pragma unroll
        for (int jt = 0; jt < 2; ++jt)
            #pragma unroll
            for (int qt = 0; qt < 4; ++qt)
                sf[jt][qt] = __builtin_amdgcn_mfma_f32_16x16x32_bf16(kf[cur][jt], qf[qt], zf, 0, 0, 0);
        __builtin_amdgcn_s_setprio(0);

        // prefetch next step's K and X frags (latency hidden behind exp/p2)
        if (s < 31) {
            #pragma unroll
            for (int jt = 0; jt < 2; ++jt)
                kf[nxt][jt] = *(const bf16x8*)(Kp + (size_t)(jb + 32 + jt * 16 + l16) * 8);
            #pragma unroll
            for (int ct = 0; ct < 4; ++ct)
                xf[nxt][ct] = *(const bf16x8*)(Xp + (size_t)(ct * 16 + l16) * N_ + jb + 32 + qd * 8);
        }

        // exp2 -> pack to wave-private LDS (denominator now via MFMA below)
        #pragma unroll
        for (int jt = 0; jt < 2; ++jt)
            #pragma unroll
            for (int qt = 0; qt < 4; ++qt) {
                float e0 = EXP2(sf[jt][qt][0]);
                float e1 = EXP2(sf[jt][qt][1]);
                float e2 = EXP2(sf[jt][qt][2]);
                float e3 = EXP2(sf[jt][qt][3]);
                uint2 u;
                u.x = pack_rtz(e0, e1);
                u.y = pack_rtz(e2, e3);
                *(uint2*)(smem + wbase + qt * 1024 + woff[jt]) = u;
            }

        // phase 2: O' += X . P^T  (A=X[m=c][k=j], B=P^T[k=j][n=q])
        //          d  += 1 . P^T  (ones-row: every out row = sum_j P[j][q])
        __builtin_amdgcn_s_setprio(1);
        #pragma unroll
        for (int qt = 0; qt < 4; ++qt) {
            bf16x8 pb = *(const bf16x8*)(smem + wbase + qt * 1024 + roff);
            acc_d[qt] = __builtin_amdgcn_mfma_f32_16x16x32_bf16(ones, pb, acc_d[qt], 0, 0, 0);
            #pragma unroll
            for (int ct = 0; ct < 4; ++ct)
                acc[ct][qt] = __builtin_amdgcn_mfma_f32_16x16x32_bf16(xf[cur][ct], pb, acc[ct][qt], 0, 0, 0);
        }
        __builtin_amdgcn_s_setprio(0);
    }

    // ---- denominator partials (already wave-reduced by the ones MFMA) ----
    #pragma unroll
    for (int qt = 0; qt < 4; ++qt)
        if (qd == 0) *(float*)(smem + 65536 + (w * 64 + qt * 16 + l16) * 4) = acc_d[qt][0];

    // ---- waves 1..3 dump O' partials ----
    if (w > 0) {
        char* rb = smem + 16384 + (w - 1) * 16384;
        #pragma unroll
        for (int ct = 0; ct < 4; ++ct)
            #pragma unroll
            for (int qt = 0; qt < 4; ++qt)
                *(f32x4*)(rb + (ct * 4 + qt) * 1024 + lane * 16) = acc[ct][qt];
    }
    __syncthreads();

    if (w == 0) {
        // reduce 3 partials, scatter O' to [c][q] fp32
        #pragma unroll
        for (int rr = 0; rr < 3; ++rr)
            #pragma unroll
            for (int ct = 0; ct < 4; ++ct)
                #pragma unroll
                for (int qt = 0; qt < 4; ++qt) {
                    f32x4 p = *(const f32x4*)(smem + 16384 + rr * 16384 + (ct * 4 + qt) * 1024 + lane * 16);
                    acc[ct][qt] += p;
                }
        float* Or = (float*)(smem + 16384);
        #pragma unroll
        for (int ct = 0; ct < 4; ++ct)
            #pragma unroll
            for (int qt = 0; qt < 4; ++qt)
                #pragma unroll
                for (int r = 0; r < 4; ++r)
                    Or[(ct * 16 + qd * 4 + r) * 64 + qt * 16 + l16] = acc[ct][qt][r];
    } else {
        // stage Wv fp32 into [0,16K) (Ps region is dead for all waves now)
        float* Wvs = (float*)smem;
        for (int i = t - 64; i < 4096; i += 192) Wvs[i] = wv[i];
    }
    __syncthreads();

    // ---- epilogue: out = Wv.O'/d + bv, fp32 ----
    const int q = t & 63, grp = t >> 6;
    const float* Wvs = (const float*)smem;
    const float* Or  = (const float*)(smem + 16384);
    const float* Dn  = (const float*)(smem + 65536);
    const float inv = 1.0f / (Dn[q] + Dn[64 + q] + Dn[128 + q] + Dn[192 + q]);
    float o[16];
    #pragma unroll
    for (int r = 0; r < 16; ++r) o[r] = 0.f;
    for (int k = 0; k < 64; ++k) {
        float ov = Or[k * 64 + q];                      // lanes consecutive q
        #pragma unroll
        for (int r = 0; r < 16; ++r)
            o[r] += Wvs[(grp * 16 + r) * 64 + k] * ov;  // broadcast
    }
    #pragma unroll
    for (int r = 0; r < 16; ++r)
        out[((size_t)b * C_ + grp * 16 + r) * N_ + i0 + q] = o[r] * inv + bv[grp * 16 + r];
}

// ---------------------------------------------------------------------------
// Fallback (workspace too small): round-1 fused fp32 flash kernel (verified).
// ---------------------------------------------------------------------------
__global__ __launch_bounds__(256) void attn_fused_fallback(
    const float* __restrict__ x,
    const float* __restrict__ wq, const float* __restrict__ bq,
    const float* __restrict__ wk, const float* __restrict__ bk,
    const float* __restrict__ wv, const float* __restrict__ bv,
    float* __restrict__ out)
{
    __shared__ float Qs[64][8];
    __shared__ float Ks[8][64];
    __shared__ float Vs[64][C_];
    __shared__ float Ws[64][64 + 1];
    __shared__ float Xs[C_ * 64];
    __shared__ float Wks[8][C_];
    __shared__ float Wvs[C_][C_ + 1];

    const int t     = threadIdx.x;
    const int b     = blockIdx.x / (N_ / 64);
    const int i0    = (blockIdx.x % (N_ / 64)) * 64;
    const int jlane = t & 63;
    const int wgrp  = t >> 6;

    for (int l = t; l < 8 * C_;  l += 256) Wks[l >> 6][l & 63] = wk[l];
    for (int l = t; l < C_ * C_; l += 256) Wvs[l >> 6][l & 63] = wv[l];
    for (int l = t; l < C_ * 64; l += 256)
        Xs[(l >> 6) * 64 + (l & 63)] = x[((size_t)b * C_ + (l >> 6)) * N_ + i0 + (l & 63)];
    __syncthreads();
    {
        int qi = jlane;
        #pragma unroll
        for (int r = 0; r < 2; ++r) {
            int cc = wgrp * 2 + r;
            float a = bq[cc];
            for (int c = 0; c < C_; ++c) a += wq[cc * C_ + c] * Xs[c * 64 + qi];
            Qs[qi][cc] = a;
        }
    }
    __syncthreads();

    const int qi2 = t >> 2;
    const int cb  = (t & 3) << 4;
    float accv[16];
    #pragma unroll
    for (int r = 0; r < 16; ++r) accv[r] = 0.f;
    float denom = 0.f;

    for (int j0 = 0; j0 < N_; j0 += 64) {
        for (int l = t; l < C_ * 64; l += 256)
            Xs[(l >> 6) * 64 + (l & 63)] = x[((size_t)b * C_ + (l >> 6)) * N_ + j0 + (l & 63)];
        __syncthreads();
        {
            int j = jlane;
            #pragma unroll
            for (int r = 0; r < 2; ++r) {
                int cc = wgrp * 2 + r;
                float a = bk[cc];
                for (int c = 0; c < C_; ++c) a += Wks[cc][c] * Xs[c * 64 + j];
                Ks[cc][j] = a;
            }
        }
        {
            int vc = jlane;
            #pragma unroll 2
            for (int r = 0; r < 16; ++r) {
                int j = wgrp * 16 + r;
                float a = bv[vc];
                for (int c = 0; c < C_; ++c) a += Wvs[vc][c] * Xs[c * 64 + j];
                Vs[j][vc] = a;
            }
        }
        __syncthreads();
        {
            float kreg[8];
            #pragma unroll
            for (int cc = 0; cc < 8; ++cc) kreg[cc] = Ks[cc][jlane];
            #pragma unroll 4
            for (int r = 0; r < 16; ++r) {
                int qi = wgrp * 16 + r;
                float e = 0.f;
                #pragma unroll
                for (int cc = 0; cc < 8; ++cc) e += Qs[qi][cc] * kreg[cc];
                Ws[qi][jlane] = __expf(e);
            }
        }
        __syncthreads();
        #pragma unroll 4
        for (int j = 0; j < 64; ++j) {
            float wv2 = Ws[qi2][j];
            denom += wv2;
            const float4* vrow = (const float4*)(&Vs[j][cb]);
            float4 v0 = vrow[0], v1 = vrow[1], v2 = vrow[2], v3 = vrow[3];
            accv[0]  += wv2 * v0.x; accv[1]  += wv2 * v0.y; accv[2]  += wv2 * v0.z; accv[3]  += wv2 * v0.w;
            accv[4]  += wv2 * v1.x; accv[5]  += wv2 * v1.y; accv[6]  += wv2 * v1.z; accv[7]  += wv2 * v1.w;
            accv[8]  += wv2 * v2.x; accv[9]  += wv2 * v2.y; accv[10] += wv2 * v2.z; accv[11] += wv2 * v2.w;
            accv[12] += wv2 * v3.x; accv[13] += wv2 * v3.y; accv[14] += wv2 * v3.z; accv[15] += wv2 * v3.w;
        }
        __syncthreads();
    }

    const float inv = 1.0f / denom;
    #pragma unroll
    for (int r = 0; r < 16; ++r)
        out[((size_t)b * C_ + cb + r) * N_ + i0 + qi2] = accv[r] * inv;
}

// ---------------------------------------------------------------------------
extern "C" void kernel_launch(void* const* d_in, const int* in_sizes, int n_in,
                              void* d_out, int out_size, void* d_ws, size_t ws_size,
                              hipStream_t stream)
{
    const float* x  = (const float*)d_in[0];
    const float* wq = (const float*)d_in[1];
    const float* bq = (const float*)d_in[2];
    const float* wk = (const float*)d_in[3];
    const float* bk = (const float*)d_in[4];
    const float* wv = (const float*)d_in[5];
    const float* bv = (const float*)d_in[6];
    float* out = (float*)d_out;

    const size_t nQ = (size_t)B_ * N_ * 8;        // 256K elems
    const size_t nX = (size_t)B_ * C_ * N_;       // 2M elems
    const size_t needed = (2 * nQ + nX) * sizeof(unsigned short);   // 5 MB

    if (ws_size >= needed) {
        unsigned short* Qh = (unsigned short*)d_ws;
        unsigned short* Kh = Qh + nQ;
        unsigned short* Xb = Kh + nQ;
        prep_kernel<<<B_ * (N_ / 64), 256, 0, stream>>>(x, wq, bq, wk, bk, Qh, Kh, Xb);
        attn_mfma6_kernel<<<B_ * (N_ / 64), 256, 0, stream>>>(Qh, Kh, Xb, wv, bv, out);
    } else {
        attn_fused_fallback<<<B_ * (N_ / 64), 256, 0, stream>>>(x, wq, bq, wk, bk, wv, bv, out);
    }
}

// Round 4
// 132.023 us; speedup vs baseline: 1.2202x; 1.0736x over previous
//
#include <hip/hip_runtime.h>
#include <hip/hip_bf16.h>

// SAGAN self-attention v8. B=8, C=64, N=4096, CQ=8.
// Algebraic refactor: out = Wv.(X.P^T)/d + bv  -- V never materialized.
// v8 = v4 per-wave code EXACT (63.2us attn; best so far) with ONE change:
//   8-wave blocks (512 thr), wave owns j-slice of 512 (16 steps x 32 j).
//   Grid stays 512 (i-tile 64). LDS 67.6KB -> still 2 blocks/CU, now
//   16 waves/CU = 4 waves/SIMD (v4: 2/SIMD). Pure latency-hiding play:
//   pipe floors (trans ~7us, MFMA ~2us chip-wide) are ~8x below the 63us
//   measured -- the kernel is latency-bound on the serial
//   MFMA->exp2->pack->write->read->MFMA chain, so resident-wave overlap
//   is the lever. v5/v6/v7 lessons: no launch_bounds min-waves (spills),
//   no setprio / ones-MFMA / unmasked-kf (v7 bundle regressed, occupancy
//   19->10), no XCD swizzle (FETCH 18.8->2.7MB proved memory is NOT the
//   wall; time got worse).

#define B_   8
#define C_   64
#define N_   4096
#define LOG2E 1.44269504088896340736f

typedef short bf16x8 __attribute__((ext_vector_type(8)));
typedef float f32x4  __attribute__((ext_vector_type(4)));
typedef unsigned int uint32;

#if __has_builtin(__builtin_amdgcn_exp2f)
#define EXP2(x) __builtin_amdgcn_exp2f(x)
#else
#define EXP2(x) __expf((x) * 0.69314718055994530942f)
#endif

__device__ __forceinline__ unsigned short f2bf_rn(float f) {
    union { __hip_bfloat16 h; unsigned short u; } cv;
    cv.h = __float2bfloat16(f);
    return cv.u;
}
__device__ __forceinline__ uint32 pk_rn(float lo, float hi) {
    return (uint32)f2bf_rn(lo) | ((uint32)f2bf_rn(hi) << 16);
}
// RTZ pack (1 v_perm): bias cancels in softmax ratio. Verified R2/R3.
__device__ __forceinline__ uint32 pack_rtz(float lo, float hi) {
    return __builtin_amdgcn_perm(__float_as_uint(hi), __float_as_uint(lo), 0x07060302);
}

// ---------------------------------------------------------------------------
// prep: UNCHANGED from v4 (byte-identical).
// ---------------------------------------------------------------------------
__global__ __launch_bounds__(256) void prep_kernel(
    const float* __restrict__ x,
    const float* __restrict__ wq, const float* __restrict__ bq,
    const float* __restrict__ wk, const float* __restrict__ bk,
    unsigned short* __restrict__ Qh, unsigned short* __restrict__ Kh,
    unsigned short* __restrict__ Xb)
{
    __shared__ float Xs[C_][64];
    __shared__ float Wqk[16][C_];
    __shared__ float Bqk[16];

    const int t  = threadIdx.x;
    const int b  = blockIdx.x >> 6;
    const int p0 = (blockIdx.x & 63) << 6;

    for (int i = t; i < 1024; i += 256) {
        int o = i >> 6;
        Wqk[o][i & 63] = (o < 8) ? wq[i] * LOG2E : wk[i - 512];
    }
    if (t < 16) Bqk[t] = (t < 8) ? bq[t] * LOG2E : bk[t - 8];

    for (int i = t; i < 2048; i += 256) {
        int c = i >> 5, p2 = (i & 31) << 1;
        const float* xp = x + ((size_t)b * C_ + c) * N_ + p0 + p2;
        float2 v = *(const float2*)xp;
        Xs[c][p2] = v.x; Xs[c][p2 + 1] = v.y;
        *(uint32*)(Xb + ((size_t)b * C_ + c) * N_ + p0 + p2) = pk_rn(v.x, v.y);
    }
    __syncthreads();

    const int pix = t & 63, grp = t >> 6;
    float a[4];
    #pragma unroll
    for (int r = 0; r < 4; ++r) a[r] = Bqk[grp * 4 + r];
    for (int c = 0; c < C_; ++c) {
        float xv = Xs[c][pix];
        #pragma unroll
        for (int r = 0; r < 4; ++r) a[r] += Wqk[grp * 4 + r][c] * xv;
    }
    #pragma unroll
    for (int r = 0; r < 4; ++r) {
        int o = grp * 4 + r;
        unsigned short hv = f2bf_rn(a[r]);
        if (o < 8) Qh[((size_t)b * N_ + p0 + pix) * 8 + o] = hv;
        else       Kh[((size_t)b * N_ + p0 + pix) * 8 + (o - 8)] = hv;
    }
}

// ---------------------------------------------------------------------------
// attn v8: grid B * N/64 = 512 blocks, 512 threads (8 waves).
// Wave w: j in [w*512, w*512+512), all 4 q-tiles, all 64 channels.
// Per-wave code identical to v4 (VGPR target: 128 -> 4 waves/SIMD).
// ---------------------------------------------------------------------------
__global__ __launch_bounds__(512) void attn_mfma7_kernel(
    const unsigned short* __restrict__ Qh,
    const unsigned short* __restrict__ Kh,
    const unsigned short* __restrict__ Xb,
    const float* __restrict__ wv, const float* __restrict__ bv,
    float* __restrict__ out)
{
    // LDS map (67584 B; 2 blocks/CU = 135KB <= 160KB):
    //  loop:    [0,32K)      P: wave w at w*4096 + qt*1024 + l16*64 + swz
    //                        (v4 layout: conflict-optimal b64/b128 cascade)
    //  epilog:  [0,64K)      stage A: waves 4-7 dump (16KB each)
    //           [16K,64K)    stage B: waves 1-3 dump
    //           [0,16K)      Wvs fp32 [64][64] (after stage-A reads done)
    //           [16K,32K)    Or fp32 [64][64] (over wave1 dump, post-read)
    //           [64K,+2K)    Dn [8][64] fp32
    __shared__ __align__(16) char smem[67584];

    const int t    = threadIdx.x;
    const int w    = t >> 6;
    const int lane = t & 63;
    const int l16  = lane & 15;
    const int qd   = lane >> 4;
    const int b    = blockIdx.x >> 6;
    const int i0   = (blockIdx.x & 63) << 6;

    const bf16x8 z8 = {};
    const f32x4  zf = {};

    // Q frags (phase-1 B-operand, B[k=ch][n=q], quads 1-3 zero: K-pad)
    bf16x8 qf[4];
    #pragma unroll
    for (int qt = 0; qt < 4; ++qt) {
        qf[qt] = z8;
        if (qd == 0)
            qf[qt] = *(const bf16x8*)(Qh + ((size_t)b * N_ + i0 + qt * 16 + l16) * 8);
    }

    const unsigned short* Kp = Kh + ((size_t)b * N_ + w * 512) * 8;
    const unsigned short* Xp = Xb + (size_t)b * C_ * N_ + w * 512;

    f32x4 acc[4][4];   // [ct][qt]: O'(c=ct*16+qd*4+r, q=qt*16+l16)
    #pragma unroll
    for (int ct = 0; ct < 4; ++ct)
        #pragma unroll
        for (int qt = 0; qt < 4; ++qt) acc[ct][qt] = zf;
    float dsum[4] = {0.f, 0.f, 0.f, 0.f};

    // wave-private P addressing, XOR-swizzled (v4-proven, conflict-optimal)
    const int swz   = (l16 & 3) << 2;
    const int wbase = w * 4096 + l16 * 64;
    int woff[2];
    #pragma unroll
    for (int jt = 0; jt < 2; ++jt) woff[jt] = ((jt * 8 + qd * 2) ^ swz) << 2;
    const int roff = ((qd * 4) ^ swz) << 2;

    // preload step 0
    bf16x8 kf[2][2], xf[2][4];
    #pragma unroll
    for (int jt = 0; jt < 2; ++jt) {
        kf[0][jt] = z8;
        if (qd == 0) kf[0][jt] = *(const bf16x8*)(Kp + (jt * 16 + l16) * 8);
    }
    #pragma unroll
    for (int ct = 0; ct < 4; ++ct)
        xf[0][ct] = *(const bf16x8*)(Xp + (size_t)(ct * 16 + l16) * N_ + qd * 8);

    #pragma unroll 2
    for (int s = 0; s < 16; ++s) {
        const int cur = s & 1, nxt = cur ^ 1;
        const int jb = s * 32;

        // phase 1: S^T[j][q] (rows j=jt*16+qd*4+r, col q=l16)
        f32x4 sf[2][4];
        #pragma unroll
        for (int jt = 0; jt < 2; ++jt)
            #pragma unroll
            for (int qt = 0; qt < 4; ++qt)
                sf[jt][qt] = __builtin_amdgcn_mfma_f32_16x16x32_bf16(kf[cur][jt], qf[qt], zf, 0, 0, 0);

        // prefetch next step's K and X frags (latency hidden behind exp/p2)
        if (s < 15) {
            #pragma unroll
            for (int jt = 0; jt < 2; ++jt) {
                bf16x8 nk = z8;
                if (qd == 0) nk = *(const bf16x8*)(Kp + (size_t)(jb + 32 + jt * 16 + l16) * 8);
                kf[nxt][jt] = nk;
            }
            #pragma unroll
            for (int ct = 0; ct < 4; ++ct)
                xf[nxt][ct] = *(const bf16x8*)(Xp + (size_t)(ct * 16 + l16) * N_ + jb + 32 + qd * 8);
        }

        // exp2 -> denom + pack to wave-private LDS
        #pragma unroll
        for (int jt = 0; jt < 2; ++jt)
            #pragma unroll
            for (int qt = 0; qt < 4; ++qt) {
                float e0 = EXP2(sf[jt][qt][0]);
                float e1 = EXP2(sf[jt][qt][1]);
                float e2 = EXP2(sf[jt][qt][2]);
                float e3 = EXP2(sf[jt][qt][3]);
                dsum[qt] += (e0 + e1) + (e2 + e3);
                uint2 u;
                u.x = pack_rtz(e0, e1);
                u.y = pack_rtz(e2, e3);
                *(uint2*)(smem + wbase + qt * 1024 + woff[jt]) = u;
            }

        // phase 2: O' += X . P^T  (A=X[m=c][k=j], B=P^T[k=j][n=q])
        #pragma unroll
        for (int qt = 0; qt < 4; ++qt) {
            bf16x8 pb = *(const bf16x8*)(smem + wbase + qt * 1024 + roff);
            #pragma unroll
            for (int ct = 0; ct < 4; ++ct)
                acc[ct][qt] = __builtin_amdgcn_mfma_f32_16x16x32_bf16(xf[cur][ct], pb, acc[ct][qt], 0, 0, 0);
        }
    }

    // ---- denominator partials -> Dn[w][64] (region untouched by loop) ----
    #pragma unroll
    for (int qt = 0; qt < 4; ++qt) {
        float v = dsum[qt];
        v += __shfl_xor(v, 16, 64);
        v += __shfl_xor(v, 32, 64);
        if (qd == 0) *(float*)(smem + 65536 + (w * 64 + qt * 16 + l16) * 4) = v;
    }

    // ---- two-stage cross-wave O' reduce (P region dead after S1) ----
    __syncthreads();                                   // S1: loop LDS done
    if (w >= 4) {                                      // stage A dump [0,64K)
        char* rb = smem + (w - 4) * 16384;
        #pragma unroll
        for (int ct = 0; ct < 4; ++ct)
            #pragma unroll
            for (int qt = 0; qt < 4; ++qt)
                *(f32x4*)(rb + (ct * 4 + qt) * 1024 + lane * 16) = acc[ct][qt];
    }
    __syncthreads();                                   // S2
    if (w < 4) {                                       // add partner w+4
        const char* rb = smem + w * 16384;
        #pragma unroll
        for (int ct = 0; ct < 4; ++ct)
            #pragma unroll
            for (int qt = 0; qt < 4; ++qt)
                acc[ct][qt] += *(const f32x4*)(rb + (ct * 4 + qt) * 1024 + lane * 16);
    }
    __syncthreads();                                   // S3: stage-A reads done
    if (w >= 1 && w < 4) {                             // stage B dump [16K,64K)
        char* rb = smem + w * 16384;
        #pragma unroll
        for (int ct = 0; ct < 4; ++ct)
            #pragma unroll
            for (int qt = 0; qt < 4; ++qt)
                *(f32x4*)(rb + (ct * 4 + qt) * 1024 + lane * 16) = acc[ct][qt];
    }
    if (w >= 4) {                                      // stage Wv -> [0,16K)
        float* Wvs = (float*)smem;
        for (int i = t - 256; i < 4096; i += 256) Wvs[i] = wv[i];
    }
    __syncthreads();                                   // S4
    if (w == 0) {                                      // final reduce + scatter
        #pragma unroll
        for (int rr = 1; rr < 4; ++rr)
            #pragma unroll
            for (int ct = 0; ct < 4; ++ct)
                #pragma unroll
                for (int qt = 0; qt < 4; ++qt) {
                    f32x4 p = *(const f32x4*)(smem + rr * 16384 + (ct * 4 + qt) * 1024 + lane * 16);
                    acc[ct][qt] += p;
                }
        float* Or = (float*)(smem + 16384);
        #pragma unroll
        for (int ct = 0; ct < 4; ++ct)
            #pragma unroll
            for (int qt = 0; qt < 4; ++qt)
                #pragma unroll
                for (int r = 0; r < 4; ++r)
                    Or[(ct * 16 + qd * 4 + r) * 64 + qt * 16 + l16] = acc[ct][qt][r];
    }
    __syncthreads();                                   // S5

    // ---- epilogue: out = Wv.O'/d + bv, fp32, all 8 waves ----
    const int q = t & 63, grp = t >> 6;                // grp = wave = c-group
    const float* Wvs = (const float*)smem;
    const float* Or  = (const float*)(smem + 16384);
    const float* Dn  = (const float*)(smem + 65536);
    float dtot = 0.f;
    #pragma unroll
    for (int r = 0; r < 8; ++r) dtot += Dn[r * 64 + q];
    const float inv = 1.0f / dtot;
    float o[8];
    #pragma unroll
    for (int r = 0; r < 8; ++r) o[r] = 0.f;
    for (int k = 0; k < 64; ++k) {
        float ov = Or[k * 64 + q];                      // lanes consecutive q
        #pragma unroll
        for (int r = 0; r < 8; ++r)
            o[r] += Wvs[(grp * 8 + r) * 64 + k] * ov;   // broadcast
    }
    #pragma unroll
    for (int r = 0; r < 8; ++r)
        out[((size_t)b * C_ + grp * 8 + r) * N_ + i0 + q] = o[r] * inv + bv[grp * 8 + r];
}

// ---------------------------------------------------------------------------
// Fallback (workspace too small): round-1 fused fp32 flash kernel (verified).
// ---------------------------------------------------------------------------
__global__ __launch_bounds__(256) void attn_fused_fallback(
    const float* __restrict__ x,
    const float* __restrict__ wq, const float* __restrict__ bq,
    const float* __restrict__ wk, const float* __restrict__ bk,
    const float* __restrict__ wv, const float* __restrict__ bv,
    float* __restrict__ out)
{
    __shared__ float Qs[64][8];
    __shared__ float Ks[8][64];
    __shared__ float Vs[64][C_];
    __shared__ float Ws[64][64 + 1];
    __shared__ float Xs[C_ * 64];
    __shared__ float Wks[8][C_];
    __shared__ float Wvs[C_][C_ + 1];

    const int t     = threadIdx.x;
    const int b     = blockIdx.x / (N_ / 64);
    const int i0    = (blockIdx.x % (N_ / 64)) * 64;
    const int jlane = t & 63;
    const int wgrp  = t >> 6;

    for (int l = t; l < 8 * C_;  l += 256) Wks[l >> 6][l & 63] = wk[l];
    for (int l = t; l < C_ * C_; l += 256) Wvs[l >> 6][l & 63] = wv[l];
    for (int l = t; l < C_ * 64; l += 256)
        Xs[(l >> 6) * 64 + (l & 63)] = x[((size_t)b * C_ + (l >> 6)) * N_ + i0 + (l & 63)];
    __syncthreads();
    {
        int qi = jlane;
        #pragma unroll
        for (int r = 0; r < 2; ++r) {
            int cc = wgrp * 2 + r;
            float a = bq[cc];
            for (int c = 0; c < C_; ++c) a += wq[cc * C_ + c] * Xs[c * 64 + qi];
            Qs[qi][cc] = a;
        }
    }
    __syncthreads();

    const int qi2 = t >> 2;
    const int cb  = (t & 3) << 4;
    float accv[16];
    #pragma unroll
    for (int r = 0; r < 16; ++r) accv[r] = 0.f;
    float denom = 0.f;

    for (int j0 = 0; j0 < N_; j0 += 64) {
        for (int l = t; l < C_ * 64; l += 256)
            Xs[(l >> 6) * 64 + (l & 63)] = x[((size_t)b * C_ + (l >> 6)) * N_ + j0 + (l & 63)];
        __syncthreads();
        {
            int j = jlane;
            #pragma unroll
            for (int r = 0; r < 2; ++r) {
                int cc = wgrp * 2 + r;
                float a = bk[cc];
                for (int c = 0; c < C_; ++c) a += Wks[cc][c] * Xs[c * 64 + j];
                Ks[cc][j] = a;
            }
        }
        {
            int vc = jlane;
            #pragma unroll 2
            for (int r = 0; r < 16; ++r) {
                int j = wgrp * 16 + r;
                float a = bv[vc];
                for (int c = 0; c < C_; ++c) a += Wvs[vc][c] * Xs[c * 64 + j];
                Vs[j][vc] = a;
            }
        }
        __syncthreads();
        {
            float kreg[8];
            #pragma unroll
            for (int cc = 0; cc < 8; ++cc) kreg[cc] = Ks[cc][jlane];
            #pragma unroll 4
            for (int r = 0; r < 16; ++r) {
                int qi = wgrp * 16 + r;
                float e = 0.f;
                #pragma unroll
                for (int cc = 0; cc < 8; ++cc) e += Qs[qi][cc] * kreg[cc];
                Ws[qi][jlane] = __expf(e);
            }
        }
        __syncthreads();
        #pragma unroll 4
        for (int j = 0; j < 64; ++j) {
            float wv2 = Ws[qi2][j];
            denom += wv2;
            const float4* vrow = (const float4*)(&Vs[j][cb]);
            float4 v0 = vrow[0], v1 = vrow[1], v2 = vrow[2], v3 = vrow[3];
            accv[0]  += wv2 * v0.x; accv[1]  += wv2 * v0.y; accv[2]  += wv2 * v0.z; accv[3]  += wv2 * v0.w;
            accv[4]  += wv2 * v1.x; accv[5]  += wv2 * v1.y; accv[6]  += wv2 * v1.z; accv[7]  += wv2 * v1.w;
            accv[8]  += wv2 * v2.x; accv[9]  += wv2 * v2.y; accv[10] += wv2 * v2.z; accv[11] += wv2 * v2.w;
            accv[12] += wv2 * v3.x; accv[13] += wv2 * v3.y; accv[14] += wv2 * v3.z; accv[15] += wv2 * v3.w;
        }
        __syncthreads();
    }

    const float inv = 1.0f / denom;
    #pragma unroll
    for (int r = 0; r < 16; ++r)
        out[((size_t)b * C_ + cb + r) * N_ + i0 + qi2] = accv[r] * inv;
}

// ---------------------------------------------------------------------------
extern "C" void kernel_launch(void* const* d_in, const int* in_sizes, int n_in,
                              void* d_out, int out_size, void* d_ws, size_t ws_size,
                              hipStream_t stream)
{
    const float* x  = (const float*)d_in[0];
    const float* wq = (const float*)d_in[1];
    const float* bq = (const float*)d_in[2];
    const float* wk = (const float*)d_in[3];
    const float* bk = (const float*)d_in[4];
    const float* wv = (const float*)d_in[5];
    const float* bv = (const float*)d_in[6];
    float* out = (float*)d_out;

    const size_t nQ = (size_t)B_ * N_ * 8;        // 256K elems
    const size_t nX = (size_t)B_ * C_ * N_;       // 2M elems
    const size_t needed = (2 * nQ + nX) * sizeof(unsigned short);   // 5 MB

    if (ws_size >= needed) {
        unsigned short* Qh = (unsigned short*)d_ws;
        unsigned short* Kh = Qh + nQ;
        unsigned short* Xb = Kh + nQ;
        prep_kernel<<<B_ * (N_ / 64), 256, 0, stream>>>(x, wq, bq, wk, bk, Qh, Kh, Xb);
        attn_mfma7_kernel<<<B_ * (N_ / 64), 512, 0, stream>>>(Qh, Kh, Xb, wv, bv, out);
    } else {
        attn_fused_fallback<<<B_ * (N_ / 64), 256, 0, stream>>>(x, wq, bq, wk, bk, wv, bv, out);
    }
}

// Round 5
// 128.749 us; speedup vs baseline: 1.2512x; 1.0254x over previous
//
#include <hip/hip_runtime.h>
#include <hip/hip_bf16.h>

// SAGAN self-attention v9. B=8, C=64, N=4096, CQ=8.
// Algebraic refactor: out = Wv.(X.P^T)/d + bv  -- V never materialized.
// v9 = v8 loop EXACT (57.6us attn; best so far) with ONE change:
//   LDS diet 67.6KB -> 34KB so 2 blocks/CU co-reside (v8's occupancy
//   counter showed 1 block/CU: 2x67.6KB didn't co-schedule). VGPR=108
//   allows 4 waves/SIMD; LDS was the only cap. Loop byte-identical;
//   epilogue reduce restructured into the dead 32KB P region in 3
//   rounds (4-7 -> 0-3 in two ct-halves, 2-3 -> 0-1 full, 1 -> 0 full).
//   This is the clean test of the latency-bound theory: any delta is
//   purely resident-wave overlap.
// Lessons kept: no launch_bounds min-waves (v5 spills), no setprio /
//   ones-MFMA / XCD swizzle (v7 bundle regressed; FETCH 18.8->2.7MB
//   proved memory is not the wall), P layout conflict-optimal (v6).

#define B_   8
#define C_   64
#define N_   4096
#define LOG2E 1.44269504088896340736f

typedef short bf16x8 __attribute__((ext_vector_type(8)));
typedef float f32x4  __attribute__((ext_vector_type(4)));
typedef unsigned int uint32;

#if __has_builtin(__builtin_amdgcn_exp2f)
#define EXP2(x) __builtin_amdgcn_exp2f(x)
#else
#define EXP2(x) __expf((x) * 0.69314718055994530942f)
#endif

__device__ __forceinline__ unsigned short f2bf_rn(float f) {
    union { __hip_bfloat16 h; unsigned short u; } cv;
    cv.h = __float2bfloat16(f);
    return cv.u;
}
__device__ __forceinline__ uint32 pk_rn(float lo, float hi) {
    return (uint32)f2bf_rn(lo) | ((uint32)f2bf_rn(hi) << 16);
}
// RTZ pack (1 v_perm): bias cancels in softmax ratio. Verified R2/R3.
__device__ __forceinline__ uint32 pack_rtz(float lo, float hi) {
    return __builtin_amdgcn_perm(__float_as_uint(hi), __float_as_uint(lo), 0x07060302);
}

// ---------------------------------------------------------------------------
// prep: UNCHANGED from v4 (byte-identical).
// ---------------------------------------------------------------------------
__global__ __launch_bounds__(256) void prep_kernel(
    const float* __restrict__ x,
    const float* __restrict__ wq, const float* __restrict__ bq,
    const float* __restrict__ wk, const float* __restrict__ bk,
    unsigned short* __restrict__ Qh, unsigned short* __restrict__ Kh,
    unsigned short* __restrict__ Xb)
{
    __shared__ float Xs[C_][64];
    __shared__ float Wqk[16][C_];
    __shared__ float Bqk[16];

    const int t  = threadIdx.x;
    const int b  = blockIdx.x >> 6;
    const int p0 = (blockIdx.x & 63) << 6;

    for (int i = t; i < 1024; i += 256) {
        int o = i >> 6;
        Wqk[o][i & 63] = (o < 8) ? wq[i] * LOG2E : wk[i - 512];
    }
    if (t < 16) Bqk[t] = (t < 8) ? bq[t] * LOG2E : bk[t - 8];

    for (int i = t; i < 2048; i += 256) {
        int c = i >> 5, p2 = (i & 31) << 1;
        const float* xp = x + ((size_t)b * C_ + c) * N_ + p0 + p2;
        float2 v = *(const float2*)xp;
        Xs[c][p2] = v.x; Xs[c][p2 + 1] = v.y;
        *(uint32*)(Xb + ((size_t)b * C_ + c) * N_ + p0 + p2) = pk_rn(v.x, v.y);
    }
    __syncthreads();

    const int pix = t & 63, grp = t >> 6;
    float a[4];
    #pragma unroll
    for (int r = 0; r < 4; ++r) a[r] = Bqk[grp * 4 + r];
    for (int c = 0; c < C_; ++c) {
        float xv = Xs[c][pix];
        #pragma unroll
        for (int r = 0; r < 4; ++r) a[r] += Wqk[grp * 4 + r][c] * xv;
    }
    #pragma unroll
    for (int r = 0; r < 4; ++r) {
        int o = grp * 4 + r;
        unsigned short hv = f2bf_rn(a[r]);
        if (o < 8) Qh[((size_t)b * N_ + p0 + pix) * 8 + o] = hv;
        else       Kh[((size_t)b * N_ + p0 + pix) * 8 + (o - 8)] = hv;
    }
}

// ---------------------------------------------------------------------------
// attn v9: grid B * N/64 = 512 blocks, 512 threads (8 waves).
// Wave w: j in [w*512, w*512+512), all 4 q-tiles, all 64 channels.
// Loop identical to v8; LDS 34816 B -> 2 blocks/CU (16 waves/CU).
// ---------------------------------------------------------------------------
__global__ __launch_bounds__(512) void attn_mfma8_kernel(
    const unsigned short* __restrict__ Qh,
    const unsigned short* __restrict__ Kh,
    const unsigned short* __restrict__ Xb,
    const float* __restrict__ wv, const float* __restrict__ bv,
    float* __restrict__ out)
{
    // LDS map (34816 B; 2 blocks/CU = 68KB, fits any plausible cap):
    //  loop:    [0,32K)    P: wave w at w*4096 + qt*1024 + l16*64 + swz
    //                      (conflict-optimal b64/b128 cascade, v4-proven)
    //  [32K,+2K)           Dn [8][64] fp32 (written post-loop, pre-S1)
    //  epilog ([0,32K) reused, P dead):
    //   R1a/b: waves 4-7 dump ct{01}/{23} 8KB @ (w-4)*8K; waves 0-3 add
    //   R2:    waves 2-3 dump full 16KB @ (w-2)*16K; waves 0-1 add
    //   R3:    wave 1 dump full @ [0,16K); wave 0 add, scatter Or->[16K,32K)
    //   then:  Wvs fp32 [64][64] -> [0,16K); GEMM epilogue (all 8 waves)
    __shared__ __align__(16) char smem[34816];

    const int t    = threadIdx.x;
    const int w    = t >> 6;
    const int lane = t & 63;
    const int l16  = lane & 15;
    const int qd   = lane >> 4;
    const int b    = blockIdx.x >> 6;
    const int i0   = (blockIdx.x & 63) << 6;

    const bf16x8 z8 = {};
    const f32x4  zf = {};

    // Q frags (phase-1 B-operand, B[k=ch][n=q], quads 1-3 zero: K-pad)
    bf16x8 qf[4];
    #pragma unroll
    for (int qt = 0; qt < 4; ++qt) {
        qf[qt] = z8;
        if (qd == 0)
            qf[qt] = *(const bf16x8*)(Qh + ((size_t)b * N_ + i0 + qt * 16 + l16) * 8);
    }

    const unsigned short* Kp = Kh + ((size_t)b * N_ + w * 512) * 8;
    const unsigned short* Xp = Xb + (size_t)b * C_ * N_ + w * 512;

    f32x4 acc[4][4];   // [ct][qt]: O'(c=ct*16+qd*4+r, q=qt*16+l16)
    #pragma unroll
    for (int ct = 0; ct < 4; ++ct)
        #pragma unroll
        for (int qt = 0; qt < 4; ++qt) acc[ct][qt] = zf;
    float dsum[4] = {0.f, 0.f, 0.f, 0.f};

    // wave-private P addressing, XOR-swizzled (v4-proven, conflict-optimal)
    const int swz   = (l16 & 3) << 2;
    const int wbase = w * 4096 + l16 * 64;
    int woff[2];
    #pragma unroll
    for (int jt = 0; jt < 2; ++jt) woff[jt] = ((jt * 8 + qd * 2) ^ swz) << 2;
    const int roff = ((qd * 4) ^ swz) << 2;

    // preload step 0
    bf16x8 kf[2][2], xf[2][4];
    #pragma unroll
    for (int jt = 0; jt < 2; ++jt) {
        kf[0][jt] = z8;
        if (qd == 0) kf[0][jt] = *(const bf16x8*)(Kp + (jt * 16 + l16) * 8);
    }
    #pragma unroll
    for (int ct = 0; ct < 4; ++ct)
        xf[0][ct] = *(const bf16x8*)(Xp + (size_t)(ct * 16 + l16) * N_ + qd * 8);

    #pragma unroll 2
    for (int s = 0; s < 16; ++s) {
        const int cur = s & 1, nxt = cur ^ 1;
        const int jb = s * 32;

        // phase 1: S^T[j][q] (rows j=jt*16+qd*4+r, col q=l16)
        f32x4 sf[2][4];
        #pragma unroll
        for (int jt = 0; jt < 2; ++jt)
            #pragma unroll
            for (int qt = 0; qt < 4; ++qt)
                sf[jt][qt] = __builtin_amdgcn_mfma_f32_16x16x32_bf16(kf[cur][jt], qf[qt], zf, 0, 0, 0);

        // prefetch next step's K and X frags (latency hidden behind exp/p2)
        if (s < 15) {
            #pragma unroll
            for (int jt = 0; jt < 2; ++jt) {
                bf16x8 nk = z8;
                if (qd == 0) nk = *(const bf16x8*)(Kp + (size_t)(jb + 32 + jt * 16 + l16) * 8);
                kf[nxt][jt] = nk;
            }
            #pragma unroll
            for (int ct = 0; ct < 4; ++ct)
                xf[nxt][ct] = *(const bf16x8*)(Xp + (size_t)(ct * 16 + l16) * N_ + jb + 32 + qd * 8);
        }

        // exp2 -> denom + pack to wave-private LDS
        #pragma unroll
        for (int jt = 0; jt < 2; ++jt)
            #pragma unroll
            for (int qt = 0; qt < 4; ++qt) {
                float e0 = EXP2(sf[jt][qt][0]);
                float e1 = EXP2(sf[jt][qt][1]);
                float e2 = EXP2(sf[jt][qt][2]);
                float e3 = EXP2(sf[jt][qt][3]);
                dsum[qt] += (e0 + e1) + (e2 + e3);
                uint2 u;
                u.x = pack_rtz(e0, e1);
                u.y = pack_rtz(e2, e3);
                *(uint2*)(smem + wbase + qt * 1024 + woff[jt]) = u;
            }

        // phase 2: O' += X . P^T  (A=X[m=c][k=j], B=P^T[k=j][n=q])
        #pragma unroll
        for (int qt = 0; qt < 4; ++qt) {
            bf16x8 pb = *(const bf16x8*)(smem + wbase + qt * 1024 + roff);
            #pragma unroll
            for (int ct = 0; ct < 4; ++ct)
                acc[ct][qt] = __builtin_amdgcn_mfma_f32_16x16x32_bf16(xf[cur][ct], pb, acc[ct][qt], 0, 0, 0);
        }
    }

    // ---- denominator partials -> Dn[w][64] at [32K,+2K) ----
    #pragma unroll
    for (int qt = 0; qt < 4; ++qt) {
        float v = dsum[qt];
        v += __shfl_xor(v, 16, 64);
        v += __shfl_xor(v, 32, 64);
        if (qd == 0) *(float*)(smem + 32768 + (w * 64 + qt * 16 + l16) * 4) = v;
    }

    // ---- cross-wave O' reduce in the dead 32KB P region ----
    __syncthreads();                                   // S1: loop LDS done
    if (w >= 4) {                                      // R1a dump ct{0,1}
        char* rb = smem + (w - 4) * 8192;
        #pragma unroll
        for (int ct = 0; ct < 2; ++ct)
            #pragma unroll
            for (int qt = 0; qt < 4; ++qt)
                *(f32x4*)(rb + (ct * 4 + qt) * 1024 + lane * 16) = acc[ct][qt];
    }
    __syncthreads();                                   // S2
    if (w < 4) {
        const char* rb = smem + w * 8192;
        #pragma unroll
        for (int ct = 0; ct < 2; ++ct)
            #pragma unroll
            for (int qt = 0; qt < 4; ++qt)
                acc[ct][qt] += *(const f32x4*)(rb + (ct * 4 + qt) * 1024 + lane * 16);
    }
    __syncthreads();                                   // S3: R1a reads done
    if (w >= 4) {                                      // R1b dump ct{2,3}
        char* rb = smem + (w - 4) * 8192;
        #pragma unroll
        for (int ct = 2; ct < 4; ++ct)
            #pragma unroll
            for (int qt = 0; qt < 4; ++qt)
                *(f32x4*)(rb + ((ct - 2) * 4 + qt) * 1024 + lane * 16) = acc[ct][qt];
    }
    __syncthreads();                                   // S4
    if (w < 4) {
        const char* rb = smem + w * 8192;
        #pragma unroll
        for (int ct = 2; ct < 4; ++ct)
            #pragma unroll
            for (int qt = 0; qt < 4; ++qt)
                acc[ct][qt] += *(const f32x4*)(rb + ((ct - 2) * 4 + qt) * 1024 + lane * 16);
    }
    __syncthreads();                                   // S5: R1b reads done
    if (w == 2 || w == 3) {                            // R2 dump full
        char* rb = smem + (w - 2) * 16384;
        #pragma unroll
        for (int ct = 0; ct < 4; ++ct)
            #pragma unroll
            for (int qt = 0; qt < 4; ++qt)
                *(f32x4*)(rb + (ct * 4 + qt) * 1024 + lane * 16) = acc[ct][qt];
    }
    __syncthreads();                                   // S6
    if (w < 2) {
        const char* rb = smem + w * 16384;
        #pragma unroll
        for (int ct = 0; ct < 4; ++ct)
            #pragma unroll
            for (int qt = 0; qt < 4; ++qt)
                acc[ct][qt] += *(const f32x4*)(rb + (ct * 4 + qt) * 1024 + lane * 16);
    }
    __syncthreads();                                   // S7: R2 reads done
    if (w == 1) {                                      // R3 dump full
        #pragma unroll
        for (int ct = 0; ct < 4; ++ct)
            #pragma unroll
            for (int qt = 0; qt < 4; ++qt)
                *(f32x4*)(smem + (ct * 4 + qt) * 1024 + lane * 16) = acc[ct][qt];
    }
    __syncthreads();                                   // S8
    if (w == 0) {                                      // final add + scatter
        #pragma unroll
        for (int ct = 0; ct < 4; ++ct)
            #pragma unroll
            for (int qt = 0; qt < 4; ++qt)
                acc[ct][qt] += *(const f32x4*)(smem + (ct * 4 + qt) * 1024 + lane * 16);
        float* Or = (float*)(smem + 16384);
        #pragma unroll
        for (int ct = 0; ct < 4; ++ct)
            #pragma unroll
            for (int qt = 0; qt < 4; ++qt)
                #pragma unroll
                for (int r = 0; r < 4; ++r)
                    Or[(ct * 16 + qd * 4 + r) * 64 + qt * 16 + l16] = acc[ct][qt][r];
    }
    __syncthreads();                                   // S9: wave0 done w/ [0,16K)
    {   // stage Wv fp32 -> [0,16K)
        float* Wvs = (float*)smem;
        for (int i = t; i < 4096; i += 512) Wvs[i] = wv[i];
    }
    __syncthreads();                                   // S10

    // ---- epilogue: out = Wv.O'/d + bv, fp32, all 8 waves ----
    const int q = t & 63, grp = t >> 6;                // grp = wave = c-group
    const float* Wvs = (const float*)smem;
    const float* Or  = (const float*)(smem + 16384);
    const float* Dn  = (const float*)(smem + 32768);
    float dtot = 0.f;
    #pragma unroll
    for (int r = 0; r < 8; ++r) dtot += Dn[r * 64 + q];
    const float inv = 1.0f / dtot;
    float o[8];
    #pragma unroll
    for (int r = 0; r < 8; ++r) o[r] = 0.f;
    for (int k = 0; k < 64; ++k) {
        float ov = Or[k * 64 + q];                      // lanes consecutive q
        #pragma unroll
        for (int r = 0; r < 8; ++r)
            o[r] += Wvs[(grp * 8 + r) * 64 + k] * ov;   // broadcast
    }
    #pragma unroll
    for (int r = 0; r < 8; ++r)
        out[((size_t)b * C_ + grp * 8 + r) * N_ + i0 + q] = o[r] * inv + bv[grp * 8 + r];
}

// ---------------------------------------------------------------------------
// Fallback (workspace too small): round-1 fused fp32 flash kernel (verified).
// ---------------------------------------------------------------------------
__global__ __launch_bounds__(256) void attn_fused_fallback(
    const float* __restrict__ x,
    const float* __restrict__ wq, const float* __restrict__ bq,
    const float* __restrict__ wk, const float* __restrict__ bk,
    const float* __restrict__ wv, const float* __restrict__ bv,
    float* __restrict__ out)
{
    __shared__ float Qs[64][8];
    __shared__ float Ks[8][64];
    __shared__ float Vs[64][C_];
    __shared__ float Ws[64][64 + 1];
    __shared__ float Xs[C_ * 64];
    __shared__ float Wks[8][C_];
    __shared__ float Wvs[C_][C_ + 1];

    const int t     = threadIdx.x;
    const int b     = blockIdx.x / (N_ / 64);
    const int i0    = (blockIdx.x % (N_ / 64)) * 64;
    const int jlane = t & 63;
    const int wgrp  = t >> 6;

    for (int l = t; l < 8 * C_;  l += 256) Wks[l >> 6][l & 63] = wk[l];
    for (int l = t; l < C_ * C_; l += 256) Wvs[l >> 6][l & 63] = wv[l];
    for (int l = t; l < C_ * 64; l += 256)
        Xs[(l >> 6) * 64 + (l & 63)] = x[((size_t)b * C_ + (l >> 6)) * N_ + i0 + (l & 63)];
    __syncthreads();
    {
        int qi = jlane;
        #pragma unroll
        for (int r = 0; r < 2; ++r) {
            int cc = wgrp * 2 + r;
            float a = bq[cc];
            for (int c = 0; c < C_; ++c) a += wq[cc * C_ + c] * Xs[c * 64 + qi];
            Qs[qi][cc] = a;
        }
    }
    __syncthreads();

    const int qi2 = t >> 2;
    const int cb  = (t & 3) << 4;
    float accv[16];
    #pragma unroll
    for (int r = 0; r < 16; ++r) accv[r] = 0.f;
    float denom = 0.f;

    for (int j0 = 0; j0 < N_; j0 += 64) {
        for (int l = t; l < C_ * 64; l += 256)
            Xs[(l >> 6) * 64 + (l & 63)] = x[((size_t)b * C_ + (l >> 6)) * N_ + j0 + (l & 63)];
        __syncthreads();
        {
            int j = jlane;
            #pragma unroll
            for (int r = 0; r < 2; ++r) {
                int cc = wgrp * 2 + r;
                float a = bk[cc];
                for (int c = 0; c < C_; ++c) a += Wks[cc][c] * Xs[c * 64 + j];
                Ks[cc][j] = a;
            }
        }
        {
            int vc = jlane;
            #pragma unroll 2
            for (int r = 0; r < 16; ++r) {
                int j = wgrp * 16 + r;
                float a = bv[vc];
                for (int c = 0; c < C_; ++c) a += Wvs[vc][c] * Xs[c * 64 + j];
                Vs[j][vc] = a;
            }
        }
        __syncthreads();
        {
            float kreg[8];
            #pragma unroll
            for (int cc = 0; cc < 8; ++cc) kreg[cc] = Ks[cc][jlane];
            #pragma unroll 4
            for (int r = 0; r < 16; ++r) {
                int qi = wgrp * 16 + r;
                float e = 0.f;
                #pragma unroll
                for (int cc = 0; cc < 8; ++cc) e += Qs[qi][cc] * kreg[cc];
                Ws[qi][jlane] = __expf(e);
            }
        }
        __syncthreads();
        #pragma unroll 4
        for (int j = 0; j < 64; ++j) {
            float wv2 = Ws[qi2][j];
            denom += wv2;
            const float4* vrow = (const float4*)(&Vs[j][cb]);
            float4 v0 = vrow[0], v1 = vrow[1], v2 = vrow[2], v3 = vrow[3];
            accv[0]  += wv2 * v0.x; accv[1]  += wv2 * v0.y; accv[2]  += wv2 * v0.z; accv[3]  += wv2 * v0.w;
            accv[4]  += wv2 * v1.x; accv[5]  += wv2 * v1.y; accv[6]  += wv2 * v1.z; accv[7]  += wv2 * v1.w;
            accv[8]  += wv2 * v2.x; accv[9]  += wv2 * v2.y; accv[10] += wv2 * v2.z; accv[11] += wv2 * v2.w;
            accv[12] += wv2 * v3.x; accv[13] += wv2 * v3.y; accv[14] += wv2 * v3.z; accv[15] += wv2 * v3.w;
        }
        __syncthreads();
    }

    const float inv = 1.0f / denom;
    #pragma unroll
    for (int r = 0; r < 16; ++r)
        out[((size_t)b * C_ + cb + r) * N_ + i0 + qi2] = accv[r] * inv;
}

// ---------------------------------------------------------------------------
extern "C" void kernel_launch(void* const* d_in, const int* in_sizes, int n_in,
                              void* d_out, int out_size, void* d_ws, size_t ws_size,
                              hipStream_t stream)
{
    const float* x  = (const float*)d_in[0];
    const float* wq = (const float*)d_in[1];
    const float* bq = (const float*)d_in[2];
    const float* wk = (const float*)d_in[3];
    const float* bk = (const float*)d_in[4];
    const float* wv = (const float*)d_in[5];
    const float* bv = (const float*)d_in[6];
    float* out = (float*)d_out;

    const size_t nQ = (size_t)B_ * N_ * 8;        // 256K elems
    const size_t nX = (size_t)B_ * C_ * N_;       // 2M elems
    const size_t needed = (2 * nQ + nX) * sizeof(unsigned short);   // 5 MB

    if (ws_size >= needed) {
        unsigned short* Qh = (unsigned short*)d_ws;
        unsigned short* Kh = Qh + nQ;
        unsigned short* Xb = Kh + nQ;
        prep_kernel<<<B_ * (N_ / 64), 256, 0, stream>>>(x, wq, bq, wk, bk, Qh, Kh, Xb);
        attn_mfma8_kernel<<<B_ * (N_ / 64), 512, 0, stream>>>(Qh, Kh, Xb, wv, bv, out);
    } else {
        attn_fused_fallback<<<B_ * (N_ / 64), 256, 0, stream>>>(x, wq, bq, wk, bk, wv, bv, out);
    }
}

// Round 6
// 123.851 us; speedup vs baseline: 1.3007x; 1.0395x over previous
//
#include <hip/hip_runtime.h>
#include <hip/hip_bf16.h>

// SAGAN self-attention v10. B=8, C=64, N=4096, CQ=8.
// Algebraic refactor: out = Wv.(X.P^T)/d + bv  -- V never materialized.
//
// OCCUPANCY MODEL (fits v4-v9 measurements): waves/SIMD =
// floor(512 / (archVGPR + AGPR)) with ~64-reg granularity; VGPR_Count
// reports ARCH ONLY. v4/v8/v9: 108-128 arch + 64 AGPR acc = 172-192
// -> 2 waves/SIMD, the real cap all along (LDS diet in v9 was null).
//
// v10: pair-split so total regs <= 128 -> 4 waves/SIMD (16 waves/CU):
//   grid 512 (b, i-tile 64), 8 waves. Pair p=w&3 owns j-slice 1024
//   (32 steps x 32 j). Within a pair, wave h=w>>2:
//     p1: S^T for jt=h only (4 MFMA + 16 exp2, half of v9's)
//     p2: O' for channel half h (acc[2][4] = 32 AGPR, xf[2][2], kf[2])
//   P shared via pair LDS buffer (dbuf, 1 barrier/step; safe: a wave
//   writes P[nxt] only after the barrier that proves all p2 reads of
//   that buffer -- issued 2 steps ago -- completed).
//   No duplicated work: chip-wide MFMA/exp2 identical to v9.
//   __launch_bounds__(512,4) enforces total<=128 (est. arch ~80, slack;
//   NOT a v5-style halving squeeze).
// Lessons kept: no setprio/ones-MFMA/XCD-swizzle (v7), P layout
//   conflict-optimal (v6), masked kf loads (v4-proven).

#define B_   8
#define C_   64
#define N_   4096
#define LOG2E 1.44269504088896340736f

typedef short bf16x8 __attribute__((ext_vector_type(8)));
typedef float f32x4  __attribute__((ext_vector_type(4)));
typedef unsigned int uint32;

#if __has_builtin(__builtin_amdgcn_exp2f)
#define EXP2(x) __builtin_amdgcn_exp2f(x)
#else
#define EXP2(x) __expf((x) * 0.69314718055994530942f)
#endif

__device__ __forceinline__ unsigned short f2bf_rn(float f) {
    union { __hip_bfloat16 h; unsigned short u; } cv;
    cv.h = __float2bfloat16(f);
    return cv.u;
}
__device__ __forceinline__ uint32 pk_rn(float lo, float hi) {
    return (uint32)f2bf_rn(lo) | ((uint32)f2bf_rn(hi) << 16);
}
// RTZ pack (1 v_perm): bias cancels in softmax ratio. Verified R2/R3.
__device__ __forceinline__ uint32 pack_rtz(float lo, float hi) {
    return __builtin_amdgcn_perm(__float_as_uint(hi), __float_as_uint(lo), 0x07060302);
}

// ---------------------------------------------------------------------------
// prep: UNCHANGED from v4 (byte-identical).
// ---------------------------------------------------------------------------
__global__ __launch_bounds__(256) void prep_kernel(
    const float* __restrict__ x,
    const float* __restrict__ wq, const float* __restrict__ bq,
    const float* __restrict__ wk, const float* __restrict__ bk,
    unsigned short* __restrict__ Qh, unsigned short* __restrict__ Kh,
    unsigned short* __restrict__ Xb)
{
    __shared__ float Xs[C_][64];
    __shared__ float Wqk[16][C_];
    __shared__ float Bqk[16];

    const int t  = threadIdx.x;
    const int b  = blockIdx.x >> 6;
    const int p0 = (blockIdx.x & 63) << 6;

    for (int i = t; i < 1024; i += 256) {
        int o = i >> 6;
        Wqk[o][i & 63] = (o < 8) ? wq[i] * LOG2E : wk[i - 512];
    }
    if (t < 16) Bqk[t] = (t < 8) ? bq[t] * LOG2E : bk[t - 8];

    for (int i = t; i < 2048; i += 256) {
        int c = i >> 5, p2 = (i & 31) << 1;
        const float* xp = x + ((size_t)b * C_ + c) * N_ + p0 + p2;
        float2 v = *(const float2*)xp;
        Xs[c][p2] = v.x; Xs[c][p2 + 1] = v.y;
        *(uint32*)(Xb + ((size_t)b * C_ + c) * N_ + p0 + p2) = pk_rn(v.x, v.y);
    }
    __syncthreads();

    const int pix = t & 63, grp = t >> 6;
    float a[4];
    #pragma unroll
    for (int r = 0; r < 4; ++r) a[r] = Bqk[grp * 4 + r];
    for (int c = 0; c < C_; ++c) {
        float xv = Xs[c][pix];
        #pragma unroll
        for (int r = 0; r < 4; ++r) a[r] += Wqk[grp * 4 + r][c] * xv;
    }
    #pragma unroll
    for (int r = 0; r < 4; ++r) {
        int o = grp * 4 + r;
        unsigned short hv = f2bf_rn(a[r]);
        if (o < 8) Qh[((size_t)b * N_ + p0 + pix) * 8 + o] = hv;
        else       Kh[((size_t)b * N_ + p0 + pix) * 8 + (o - 8)] = hv;
    }
}

// ---------------------------------------------------------------------------
// attn v10: grid B * N/64 = 512 blocks, 512 threads (8 waves = 4 pairs).
// Pair p: j in [p*1024, +1024), 32 steps x 32 j. Wave h of pair: jt=h in
// phase 1, channel half h (c in [h*32, h*32+32)) in phase 2.
// ---------------------------------------------------------------------------
__global__ __launch_bounds__(512, 4) void attn_mfma9_kernel(
    const unsigned short* __restrict__ Qh,
    const unsigned short* __restrict__ Kh,
    const unsigned short* __restrict__ Xb,
    const float* __restrict__ wv, const float* __restrict__ bv,
    float* __restrict__ out)
{
    // LDS map (67584 B; 2 blocks/CU = 135KB <= 160KB, v4 precedent 133KB):
    //  loop:   [0,32K)   P: pair p at p*8192, dbuf +cur*4096; inside:
    //                    qt*1024 + l16*64 + XOR-swz offs (v4 layout,
    //                    conflict-optimal). jt0 dwords and jt1 dwords are
    //                    disjoint under the swz (differ in dword bit 3).
    //  epilog: [0,48K)   6 dump slots x 8KB (w1,w2,w3 -> 0,1,2; w5,w6,w7
    //                    -> 3,4,5); then [0,16K) Wvs after reads done
    //          [48K,64K) Or fp32 [64][64]
    //          [64K,+2K) Dn [8][64] fp32
    __shared__ __align__(16) char smem[67584];

    const int t    = threadIdx.x;
    const int w    = t >> 6;
    const int lane = t & 63;
    const int l16  = lane & 15;
    const int qd   = lane >> 4;
    const int p    = w & 3;     // pair -> j-slice
    const int h    = w >> 2;    // 0: jt0 + c[0,32) ; 1: jt1 + c[32,64)
    const int b    = blockIdx.x >> 6;
    const int i0   = (blockIdx.x & 63) << 6;

    const bf16x8 z8 = {};
    const f32x4  zf = {};

    // Q frags (phase-1 B-operand, B[k=ch][n=q], quads 1-3 zero: K-pad)
    bf16x8 qf[4];
    #pragma unroll
    for (int qt = 0; qt < 4; ++qt) {
        qf[qt] = z8;
        if (qd == 0)
            qf[qt] = *(const bf16x8*)(Qh + ((size_t)b * N_ + i0 + qt * 16 + l16) * 8);
    }

    // K rows for this wave's jt-half only; X rows for its channel half.
    const unsigned short* Kp = Kh + ((size_t)b * N_ + p * 1024 + h * 16) * 8;
    const unsigned short* Xp = Xb + ((size_t)b * C_ + h * 32) * N_ + p * 1024;

    f32x4 acc[2][4];   // [ct][qt]: O'(c=h*32+ct*16+qd*4+r, q=qt*16+l16)
    #pragma unroll
    for (int ct = 0; ct < 2; ++ct)
        #pragma unroll
        for (int qt = 0; qt < 4; ++qt) acc[ct][qt] = zf;
    float dsum[4] = {0.f, 0.f, 0.f, 0.f};

    // P addressing (v4-proven XOR swizzle); this wave writes its jt=h rows.
    const int swz   = (l16 & 3) << 2;
    const int pbase = p * 8192 + l16 * 64;
    const int woff  = ((h * 8 + qd * 2) ^ swz) << 2;
    const int roff  = ((qd * 4) ^ swz) << 2;

    // preload step 0
    bf16x8 kf[2], xf[2][2];
    kf[0] = z8;
    if (qd == 0) kf[0] = *(const bf16x8*)(Kp + (size_t)l16 * 8);
    #pragma unroll
    for (int ct = 0; ct < 2; ++ct)
        xf[0][ct] = *(const bf16x8*)(Xp + (size_t)(ct * 16 + l16) * N_ + qd * 8);

    #pragma unroll 2
    for (int s = 0; s < 32; ++s) {
        const int cur = s & 1, nxt = cur ^ 1;
        const int jb = s * 32;
        char* pb_ = smem + pbase + cur * 4096;

        // phase 1: S^T[j][q] for jt=h (rows j=jb+h*16+qd*4+r, col q=l16)
        f32x4 sf[4];
        #pragma unroll
        for (int qt = 0; qt < 4; ++qt)
            sf[qt] = __builtin_amdgcn_mfma_f32_16x16x32_bf16(kf[cur], qf[qt], zf, 0, 0, 0);

        // prefetch next step's K and X frags
        if (s < 31) {
            bf16x8 nk = z8;
            if (qd == 0) nk = *(const bf16x8*)(Kp + (size_t)(jb + 32 + l16) * 8);
            kf[nxt] = nk;
            #pragma unroll
            for (int ct = 0; ct < 2; ++ct)
                xf[nxt][ct] = *(const bf16x8*)(Xp + (size_t)(ct * 16 + l16) * N_ + jb + 32 + qd * 8);
        }

        // exp2 -> denom + pack this wave's jt-half into the pair P buffer
        #pragma unroll
        for (int qt = 0; qt < 4; ++qt) {
            float e0 = EXP2(sf[qt][0]);
            float e1 = EXP2(sf[qt][1]);
            float e2 = EXP2(sf[qt][2]);
            float e3 = EXP2(sf[qt][3]);
            dsum[qt] += (e0 + e1) + (e2 + e3);
            uint2 u;
            u.x = pack_rtz(e0, e1);
            u.y = pack_rtz(e2, e3);
            *(uint2*)(pb_ + qt * 1024 + woff) = u;
        }

        // pair handshake: P[cur] complete (both jt halves) after this.
        // Overwrite of P[nxt] next step is safe: its readers (p2 of step
        // s-1) finished before this barrier (syncthreads drains lgkm).
        __syncthreads();

        // phase 2: O'(half h) += X . P^T, full 32-j slice from pair buffer
        #pragma unroll
        for (int qt = 0; qt < 4; ++qt) {
            bf16x8 pbf = *(const bf16x8*)(pb_ + qt * 1024 + roff);
            #pragma unroll
            for (int ct = 0; ct < 2; ++ct)
                acc[ct][qt] = __builtin_amdgcn_mfma_f32_16x16x32_bf16(xf[cur][ct], pbf, acc[ct][qt], 0, 0, 0);
        }
    }

    // ---- denominator partials -> Dn[w][64] at [64K,+2K) ----
    #pragma unroll
    for (int qt = 0; qt < 4; ++qt) {
        float v = dsum[qt];
        v += __shfl_xor(v, 16, 64);
        v += __shfl_xor(v, 32, 64);
        if (qd == 0) *(float*)(smem + 65536 + (w * 64 + qt * 16 + l16) * 4) = v;
    }

    // ---- cross-wave O' reduce: halves reduce independently ----
    __syncthreads();                                   // S1: loop LDS done
    if (p != 0) {                                      // 6 dumpers, 8KB each
        const int slot = h * 3 + (p - 1);
        char* rb = smem + slot * 8192;
        #pragma unroll
        for (int ct = 0; ct < 2; ++ct)
            #pragma unroll
            for (int qt = 0; qt < 4; ++qt)
                *(f32x4*)(rb + (ct * 4 + qt) * 1024 + lane * 16) = acc[ct][qt];
    }
    __syncthreads();                                   // S2
    if (p == 0) {                                      // w0 (ct01), w4 (ct23)
        #pragma unroll
        for (int rr = 0; rr < 3; ++rr) {
            const char* rb = smem + (h * 3 + rr) * 8192;
            #pragma unroll
            for (int ct = 0; ct < 2; ++ct)
                #pragma unroll
                for (int qt = 0; qt < 4; ++qt)
                    acc[ct][qt] += *(const f32x4*)(rb + (ct * 4 + qt) * 1024 + lane * 16);
        }
        float* Or = (float*)(smem + 49152);
        #pragma unroll
        for (int ct = 0; ct < 2; ++ct)
            #pragma unroll
            for (int qt = 0; qt < 4; ++qt)
                #pragma unroll
                for (int r = 0; r < 4; ++r)
                    Or[(h * 32 + ct * 16 + qd * 4 + r) * 64 + qt * 16 + l16] = acc[ct][qt][r];
    }
    __syncthreads();                                   // S3: dump reads done
    {   // stage Wv fp32 -> [0,16K)
        float* Wvs = (float*)smem;
        for (int i = t; i < 4096; i += 512) Wvs[i] = wv[i];
    }
    __syncthreads();                                   // S4

    // ---- epilogue: out = Wv.O'/d + bv, fp32, all 8 waves ----
    const int q = t & 63, grp = t >> 6;                // grp = wave = c-group
    const float* Wvs = (const float*)smem;
    const float* Or  = (const float*)(smem + 49152);
    const float* Dn  = (const float*)(smem + 65536);
    float dtot = 0.f;
    #pragma unroll
    for (int r = 0; r < 8; ++r) dtot += Dn[r * 64 + q];
    const float inv = 1.0f / dtot;
    float o[8];
    #pragma unroll
    for (int r = 0; r < 8; ++r) o[r] = 0.f;
    for (int k = 0; k < 64; ++k) {
        float ov = Or[k * 64 + q];                      // lanes consecutive q
        #pragma unroll
        for (int r = 0; r < 8; ++r)
            o[r] += Wvs[(grp * 8 + r) * 64 + k] * ov;   // broadcast
    }
    #pragma unroll
    for (int r = 0; r < 8; ++r)
        out[((size_t)b * C_ + grp * 8 + r) * N_ + i0 + q] = o[r] * inv + bv[grp * 8 + r];
}

// ---------------------------------------------------------------------------
// Fallback (workspace too small): round-1 fused fp32 flash kernel (verified).
// ---------------------------------------------------------------------------
__global__ __launch_bounds__(256) void attn_fused_fallback(
    const float* __restrict__ x,
    const float* __restrict__ wq, const float* __restrict__ bq,
    const float* __restrict__ wk, const float* __restrict__ bk,
    const float* __restrict__ wv, const float* __restrict__ bv,
    float* __restrict__ out)
{
    __shared__ float Qs[64][8];
    __shared__ float Ks[8][64];
    __shared__ float Vs[64][C_];
    __shared__ float Ws[64][64 + 1];
    __shared__ float Xs[C_ * 64];
    __shared__ float Wks[8][C_];
    __shared__ float Wvs[C_][C_ + 1];

    const int t     = threadIdx.x;
    const int b     = blockIdx.x / (N_ / 64);
    const int i0    = (blockIdx.x % (N_ / 64)) * 64;
    const int jlane = t & 63;
    const int wgrp  = t >> 6;

    for (int l = t; l < 8 * C_;  l += 256) Wks[l >> 6][l & 63] = wk[l];
    for (int l = t; l < C_ * C_; l += 256) Wvs[l >> 6][l & 63] = wv[l];
    for (int l = t; l < C_ * 64; l += 256)
        Xs[(l >> 6) * 64 + (l & 63)] = x[((size_t)b * C_ + (l >> 6)) * N_ + i0 + (l & 63)];
    __syncthreads();
    {
        int qi = jlane;
        #pragma unroll
        for (int r = 0; r < 2; ++r) {
            int cc = wgrp * 2 + r;
            float a = bq[cc];
            for (int c = 0; c < C_; ++c) a += wq[cc * C_ + c] * Xs[c * 64 + qi];
            Qs[qi][cc] = a;
        }
    }
    __syncthreads();

    const int qi2 = t >> 2;
    const int cb  = (t & 3) << 4;
    float accv[16];
    #pragma unroll
    for (int r = 0; r < 16; ++r) accv[r] = 0.f;
    float denom = 0.f;

    for (int j0 = 0; j0 < N_; j0 += 64) {
        for (int l = t; l < C_ * 64; l += 256)
            Xs[(l >> 6) * 64 + (l & 63)] = x[((size_t)b * C_ + (l >> 6)) * N_ + j0 + (l & 63)];
        __syncthreads();
        {
            int j = jlane;
            #pragma unroll
            for (int r = 0; r < 2; ++r) {
                int cc = wgrp * 2 + r;
                float a = bk[cc];
                for (int c = 0; c < C_; ++c) a += Wks[cc][c] * Xs[c * 64 + j];
                Ks[cc][j] = a;
            }
        }
        {
            int vc = jlane;
            #pragma unroll 2
            for (int r = 0; r < 16; ++r) {
                int j = wgrp * 16 + r;
                float a = bv[vc];
                for (int c = 0; c < C_; ++c) a += Wvs[vc][c] * Xs[c * 64 + j];
                Vs[j][vc] = a;
            }
        }
        __syncthreads();
        {
            float kreg[8];
            #pragma unroll
            for (int cc = 0; cc < 8; ++cc) kreg[cc] = Ks[cc][jlane];
            #pragma unroll 4
            for (int r = 0; r < 16; ++r) {
                int qi = wgrp * 16 + r;
                float e = 0.f;
                #pragma unroll
                for (int cc = 0; cc < 8; ++cc) e += Qs[qi][cc] * kreg[cc];
                Ws[qi][jlane] = __expf(e);
            }
        }
        __syncthreads();
        #pragma unroll 4
        for (int j = 0; j < 64; ++j) {
            float wv2 = Ws[qi2][j];
            denom += wv2;
            const float4* vrow = (const float4*)(&Vs[j][cb]);
            float4 v0 = vrow[0], v1 = vrow[1], v2 = vrow[2], v3 = vrow[3];
            accv[0]  += wv2 * v0.x; accv[1]  += wv2 * v0.y; accv[2]  += wv2 * v0.z; accv[3]  += wv2 * v0.w;
            accv[4]  += wv2 * v1.x; accv[5]  += wv2 * v1.y; accv[6]  += wv2 * v1.z; accv[7]  += wv2 * v1.w;
            accv[8]  += wv2 * v2.x; accv[9]  += wv2 * v2.y; accv[10] += wv2 * v2.z; accv[11] += wv2 * v2.w;
            accv[12] += wv2 * v3.x; accv[13] += wv2 * v3.y; accv[14] += wv2 * v3.z; accv[15] += wv2 * v3.w;
        }
        __syncthreads();
    }

    const float inv = 1.0f / denom;
    #pragma unroll
    for (int r = 0; r < 16; ++r)
        out[((size_t)b * C_ + cb + r) * N_ + i0 + qi2] = accv[r] * inv;
}

// ---------------------------------------------------------------------------
extern "C" void kernel_launch(void* const* d_in, const int* in_sizes, int n_in,
                              void* d_out, int out_size, void* d_ws, size_t ws_size,
                              hipStream_t stream)
{
    const float* x  = (const float*)d_in[0];
    const float* wq = (const float*)d_in[1];
    const float* bq = (const float*)d_in[2];
    const float* wk = (const float*)d_in[3];
    const float* bk = (const float*)d_in[4];
    const float* wv = (const float*)d_in[5];
    const float* bv = (const float*)d_in[6];
    float* out = (float*)d_out;

    const size_t nQ = (size_t)B_ * N_ * 8;        // 256K elems
    const size_t nX = (size_t)B_ * C_ * N_;       // 2M elems
    const size_t needed = (2 * nQ + nX) * sizeof(unsigned short);   // 5 MB

    if (ws_size >= needed) {
        unsigned short* Qh = (unsigned short*)d_ws;
        unsigned short* Kh = Qh + nQ;
        unsigned short* Xb = Kh + nQ;
        prep_kernel<<<B_ * (N_ / 64), 256, 0, stream>>>(x, wq, bq, wk, bk, Qh, Kh, Xb);
        attn_mfma9_kernel<<<B_ * (N_ / 64), 512, 0, stream>>>(Qh, Kh, Xb, wv, bv, out);
    } else {
        attn_fused_fallback<<<B_ * (N_ / 64), 256, 0, stream>>>(x, wq, bq, wk, bk, wv, bv, out);
    }
}